// Round 2
// baseline (609.520 us; speedup 1.0000x reference)
//
#include <hip/hip_runtime.h>
#include <hip/hip_bf16.h>

typedef short bf16x8 __attribute__((ext_vector_type(8)));
typedef float f32x4  __attribute__((ext_vector_type(4)));

#define LSEQ 2048
#define DDIM 512
#define NBAT 8

// ---------------- convert x fp32 -> bf16 ----------------
__global__ void k_cvt_x(const float* __restrict__ x, __hip_bfloat16* __restrict__ xb) {
    size_t i = ((size_t)blockIdx.x * 256 + threadIdx.x) * 4;
    float4 v = *(const float4*)(x + i);
    __hip_bfloat16 h[4] = { __float2bfloat16(v.x), __float2bfloat16(v.y),
                            __float2bfloat16(v.z), __float2bfloat16(v.w) };
    *(short4*)(xb + i) = *(short4*)h;
}

// ---------------- convert + transpose weights ----------------
__global__ void k_cvt_w(const float* __restrict__ Wq, const float* __restrict__ Wk,
                        const float* __restrict__ Wv, const float* __restrict__ Wo,
                        __hip_bfloat16* __restrict__ Wtqkv, __hip_bfloat16* __restrict__ Wto) {
    __shared__ float t[32][33];
    int mat = blockIdx.x >> 8;
    int tb  = blockIdx.x & 255;
    int tk  = tb >> 4, tn = tb & 15;
    const float* W = (mat == 0) ? Wq : (mat == 1) ? Wk : (mat == 2) ? Wv : Wo;
    int c  = threadIdx.x & 31;
    int r0 = threadIdx.x >> 5;
#pragma unroll
    for (int i = 0; i < 4; ++i) {
        int r = r0 + i * 8;
        t[r][c] = W[(size_t)(tk * 32 + r) * 512 + tn * 32 + c];
    }
    __syncthreads();
    __hip_bfloat16* dst = (mat < 3) ? (Wtqkv + (size_t)mat * 512 * 512) : Wto;
#pragma unroll
    for (int i = 0; i < 4; ++i) {
        int n = r0 + i * 8;
        dst[(size_t)(tn * 32 + n) * 512 + tk * 32 + c] = __float2bfloat16(t[c][n]);
    }
}

// ---------------- fused QKV GEMM: C = xb @ [Wq|Wk|Wv]  (Bt form) ----------------
__global__ __launch_bounds__(256, 2)
void k_gemm_qkv(const __hip_bfloat16* __restrict__ A, const __hip_bfloat16* __restrict__ Bt,
                __hip_bfloat16* __restrict__ Q, __hip_bfloat16* __restrict__ Kb,
                __hip_bfloat16* __restrict__ Vt) {
    __shared__ char As[8192], Bs[8192];
    const int tid = threadIdx.x, lane = tid & 63, w = tid >> 6;
    const int l15 = lane & 15, l4 = lane >> 4;
    const int mt = blockIdx.x, nt = blockIdx.y;
    const int wr = (w >> 1) * 64, wc = (w & 1) * 64;
    f32x4 acc[4][4] = {};
    const int c0 = tid, c1 = tid + 256;
    const int r0 = c0 >> 2, o0 = c0 & 3, r1 = c1 >> 2, o1 = c1 & 3;

#pragma unroll 1
    for (int kt = 0; kt < 16; ++kt) {
        __syncthreads();
        bf16x8 a0 = *(const bf16x8*)(A + (size_t)(mt * 128 + r0) * 512 + kt * 32 + o0 * 8);
        bf16x8 a1 = *(const bf16x8*)(A + (size_t)(mt * 128 + r1) * 512 + kt * 32 + o1 * 8);
        bf16x8 b0 = *(const bf16x8*)(Bt + (size_t)(nt * 128 + r0) * 512 + kt * 32 + o0 * 8);
        bf16x8 b1 = *(const bf16x8*)(Bt + (size_t)(nt * 128 + r1) * 512 + kt * 32 + o1 * 8);
        *(bf16x8*)(As + r0 * 64 + ((o0 * 16) ^ ((((r0 >> 1) & 3)) << 4))) = a0;
        *(bf16x8*)(As + r1 * 64 + ((o1 * 16) ^ ((((r1 >> 1) & 3)) << 4))) = a1;
        *(bf16x8*)(Bs + r0 * 64 + ((o0 * 16) ^ ((((r0 >> 1) & 3)) << 4))) = b0;
        *(bf16x8*)(Bs + r1 * 64 + ((o1 * 16) ^ ((((r1 >> 1) & 3)) << 4))) = b1;
        __syncthreads();
        bf16x8 af[4], bfr[4];
#pragma unroll
        for (int i = 0; i < 4; ++i) {
            int r = wr + 16 * i + l15;
            af[i] = *(const bf16x8*)(As + r * 64 + ((16 * l4) ^ ((((r >> 1) & 3)) << 4)));
        }
#pragma unroll
        for (int j = 0; j < 4; ++j) {
            int r = wc + 16 * j + l15;
            bfr[j] = *(const bf16x8*)(Bs + r * 64 + ((16 * l4) ^ ((((r >> 1) & 3)) << 4)));
        }
#pragma unroll
        for (int i = 0; i < 4; ++i)
#pragma unroll
            for (int j = 0; j < 4; ++j)
                acc[i][j] = __builtin_amdgcn_mfma_f32_16x16x32_bf16(af[i], bfr[j], acc[i][j], 0, 0, 0);
    }
    const int which = (nt * 128) >> 9;  // uniform per block (0=q,1=k,2=v)
#pragma unroll
    for (int i = 0; i < 4; ++i) {
#pragma unroll
        for (int r = 0; r < 4; ++r) {
            int grow = mt * 128 + wr + 16 * i + (l4 << 2) + r;
#pragma unroll
            for (int j = 0; j < 4; ++j) {
                int gcol = nt * 128 + wc + 16 * j + l15;
                int cc = gcol & 511;
                __hip_bfloat16 h = __float2bfloat16(acc[i][j][r]);
                if (which == 0)      Q [(size_t)grow * 512 + cc] = h;
                else if (which == 1) Kb[(size_t)grow * 512 + cc] = h;
                else {
                    int b = grow >> 11, m = grow & 2047;
                    Vt[((size_t)b * 512 + cc) * 2048 + m] = h;
                }
            }
        }
    }
}

// ---------------- flash attention with adj mask (KVB=32, 2 blocks/CU) ----------------
// grid 256: b = blk&7 (XCD affinity), qt = blk>>3. 4 waves x 16 q-rows, KVB=32.
__global__ __launch_bounds__(256, 2)
void k_attn(const __hip_bfloat16* __restrict__ Q, const __hip_bfloat16* __restrict__ Kg,
            const __hip_bfloat16* __restrict__ Vt, const int* __restrict__ adj,
            __hip_bfloat16* __restrict__ O) {
    __shared__ __hip_bfloat16 Kl[32][520];    // 33,280 B (row stride 1040B: 65x16B, rotates banks)
    __shared__ __hip_bfloat16 Vl[512][40];    // 40,960 B (row stride 80B: 5x16B, rotates banks)
    __shared__ __hip_bfloat16 Pl[4][16][40];  // 5,120 B per-wave P relayout
    const int tid = threadIdx.x, lane = tid & 63, w = tid >> 6;
    const int l15 = lane & 15, l4 = lane >> 4;
    const int b = blockIdx.x & 7, qt = blockIdx.x >> 3;
    const float scale = 0.04419417382415922f;  // 1/sqrt(512)

    // Q fragments in registers: wave's 16 rows x 512 k
    bf16x8 qf[16];
    {
        const __hip_bfloat16* qp = Q + ((size_t)b * LSEQ + qt * 64 + w * 16 + l15) * 512;
#pragma unroll
        for (int ks = 0; ks < 16; ++ks)
            qf[ks] = *(const bf16x8*)(qp + ks * 32 + l4 * 8);
    }
    f32x4 acc[32];
#pragma unroll
    for (int n = 0; n < 32; ++n) acc[n] = (f32x4){0.f, 0.f, 0.f, 0.f};
    float m_[4] = {-1e30f, -1e30f, -1e30f, -1e30f};
    float l_[4] = {0.f, 0.f, 0.f, 0.f};

#pragma unroll 1
    for (int kt = 0; kt < 64; ++kt) {
        __syncthreads();
        // stage K tile (32 rows x 512 k)
        {
            const __hip_bfloat16* kp = Kg + ((size_t)b * LSEQ + kt * 32) * 512;
#pragma unroll
            for (int i = 0; i < 8; ++i) {
                int c = tid + i * 256;
                int r = c >> 6, o = c & 63;
                bf16x8 v = *(const bf16x8*)(kp + (size_t)r * 512 + o * 8);
                *(bf16x8*)(&Kl[r][o * 8]) = v;
            }
        }
        // stage V tile (512 d-rows x 32 m) from Vt
        {
            const __hip_bfloat16* vp = Vt + (size_t)b * 512 * 2048 + kt * 32;
#pragma unroll
            for (int i = 0; i < 8; ++i) {
                int c = tid + i * 256;
                int r = c >> 2, o = c & 3;
                bf16x8 v = *(const bf16x8*)(vp + (size_t)r * 2048 + o * 8);
                *(bf16x8*)(&Vl[r][o * 8]) = v;
            }
        }
        // adj bits for this wave's 16 rows x 32 cols
        unsigned amask = 0;
        {
            const int* ap = adj + ((size_t)b * LSEQ + qt * 64 + w * 16 + l4 * 4) * LSEQ + kt * 32 + l15;
#pragma unroll
            for (int r = 0; r < 4; ++r)
#pragma unroll
                for (int n = 0; n < 2; ++n) {
                    int a = ap[(size_t)r * LSEQ + n * 16];
                    amask |= (a != 0 ? 1u : 0u) << (n * 4 + r);
                }
        }
        __syncthreads();
        // scores: S = Q . K^T for wave's 16 rows x 32 keys
        f32x4 sa[2];
#pragma unroll
        for (int n = 0; n < 2; ++n) sa[n] = (f32x4){0.f, 0.f, 0.f, 0.f};
        __builtin_amdgcn_s_setprio(1);
#pragma unroll
        for (int ks = 0; ks < 16; ++ks) {
#pragma unroll
            for (int n = 0; n < 2; ++n) {
                bf16x8 bk = *(const bf16x8*)(&Kl[n * 16 + l15][ks * 32 + l4 * 8]);
                sa[n] = __builtin_amdgcn_mfma_f32_16x16x32_bf16(qf[ks], bk, sa[n], 0, 0, 0);
            }
        }
        __builtin_amdgcn_s_setprio(0);
        // masked row max (across the 16-lane group)
        float mx[4];
#pragma unroll
        for (int r = 0; r < 4; ++r) {
            float v = -1e30f;
#pragma unroll
            for (int n = 0; n < 2; ++n)
                if ((amask >> (n * 4 + r)) & 1) v = fmaxf(v, sa[n][r] * scale);
            v = fmaxf(v, __shfl_xor(v, 1));
            v = fmaxf(v, __shfl_xor(v, 2));
            v = fmaxf(v, __shfl_xor(v, 4));
            v = fmaxf(v, __shfl_xor(v, 8));
            mx[r] = v;
        }
        // deferred-max online softmax update (THR=8)
        float rs[4];
        bool need = false;
#pragma unroll
        for (int r = 0; r < 4; ++r) {
            rs[r] = 1.f;
            if (mx[r] > m_[r] + 8.f) { rs[r] = __expf(m_[r] - mx[r]); m_[r] = mx[r]; }
            l_[r] *= rs[r];
            need |= (rs[r] != 1.f);
        }
        if (need) {
#pragma unroll
            for (int n = 0; n < 32; ++n) {
                acc[n][0] *= rs[0]; acc[n][1] *= rs[1];
                acc[n][2] *= rs[2]; acc[n][3] *= rs[3];
            }
        }
        // p = exp(s - m) (masked -> 0); row sums
#pragma unroll
        for (int n = 0; n < 2; ++n)
#pragma unroll
            for (int r = 0; r < 4; ++r) {
                float p = ((amask >> (n * 4 + r)) & 1) ? __expf(sa[n][r] * scale - m_[r]) : 0.f;
                sa[n][r] = p;
            }
#pragma unroll
        for (int r = 0; r < 4; ++r) {
            float s = sa[0][r] + sa[1][r];
            s += __shfl_xor(s, 1);
            s += __shfl_xor(s, 2);
            s += __shfl_xor(s, 4);
            s += __shfl_xor(s, 8);
            l_[r] += s;
        }
        // relayout P via per-wave LDS into A-frags
#pragma unroll
        for (int n = 0; n < 2; ++n)
#pragma unroll
            for (int r = 0; r < 4; ++r)
                Pl[w][l4 * 4 + r][n * 16 + l15] = __float2bfloat16(sa[n][r]);
        // PV accumulate: acc += P @ V  (Bt form via Vl), single K-step of 32
        {
            bf16x8 pf = *(const bf16x8*)(&Pl[w][l15][l4 * 8]);
            __builtin_amdgcn_s_setprio(1);
#pragma unroll
            for (int n = 0; n < 32; ++n) {
                bf16x8 bv = *(const bf16x8*)(&Vl[n * 16 + l15][l4 * 8]);
                acc[n] = __builtin_amdgcn_mfma_f32_16x16x32_bf16(pf, bv, acc[n], 0, 0, 0);
            }
            __builtin_amdgcn_s_setprio(0);
        }
    }
    // epilogue: O = acc / l
#pragma unroll
    for (int r = 0; r < 4; ++r) {
        float inv = (l_[r] > 0.f) ? 1.f / l_[r] : 0.f;
        size_t row = (size_t)b * LSEQ + qt * 64 + w * 16 + l4 * 4 + r;
#pragma unroll
        for (int n = 0; n < 32; ++n)
            O[row * 512 + n * 16 + l15] = __float2bfloat16(acc[n][r] * inv);
    }
}

// ---------------- out projection + residual + bias -> Y fp32 (into d_out) ----------------
__global__ __launch_bounds__(256, 2)
void k_gemm_out(const __hip_bfloat16* __restrict__ A, const __hip_bfloat16* __restrict__ Bt,
                const float* __restrict__ x, const float* __restrict__ bo,
                float* __restrict__ Y) {
    __shared__ char As[8192], Bs[8192];
    const int tid = threadIdx.x, lane = tid & 63, w = tid >> 6;
    const int l15 = lane & 15, l4 = lane >> 4;
    const int mt = blockIdx.x, nt = blockIdx.y;
    const int wr = (w >> 1) * 64, wc = (w & 1) * 64;
    f32x4 acc[4][4] = {};
    const int c0 = tid, c1 = tid + 256;
    const int r0 = c0 >> 2, o0 = c0 & 3, r1 = c1 >> 2, o1 = c1 & 3;

#pragma unroll 1
    for (int kt = 0; kt < 16; ++kt) {
        __syncthreads();
        bf16x8 a0 = *(const bf16x8*)(A + (size_t)(mt * 128 + r0) * 512 + kt * 32 + o0 * 8);
        bf16x8 a1 = *(const bf16x8*)(A + (size_t)(mt * 128 + r1) * 512 + kt * 32 + o1 * 8);
        bf16x8 b0 = *(const bf16x8*)(Bt + (size_t)(nt * 128 + r0) * 512 + kt * 32 + o0 * 8);
        bf16x8 b1 = *(const bf16x8*)(Bt + (size_t)(nt * 128 + r1) * 512 + kt * 32 + o1 * 8);
        *(bf16x8*)(As + r0 * 64 + ((o0 * 16) ^ ((((r0 >> 1) & 3)) << 4))) = a0;
        *(bf16x8*)(As + r1 * 64 + ((o1 * 16) ^ ((((r1 >> 1) & 3)) << 4))) = a1;
        *(bf16x8*)(Bs + r0 * 64 + ((o0 * 16) ^ ((((r0 >> 1) & 3)) << 4))) = b0;
        *(bf16x8*)(Bs + r1 * 64 + ((o1 * 16) ^ ((((r1 >> 1) & 3)) << 4))) = b1;
        __syncthreads();
        bf16x8 af[4], bfr[4];
#pragma unroll
        for (int i = 0; i < 4; ++i) {
            int r = wr + 16 * i + l15;
            af[i] = *(const bf16x8*)(As + r * 64 + ((16 * l4) ^ ((((r >> 1) & 3)) << 4)));
        }
#pragma unroll
        for (int j = 0; j < 4; ++j) {
            int r = wc + 16 * j + l15;
            bfr[j] = *(const bf16x8*)(Bs + r * 64 + ((16 * l4) ^ ((((r >> 1) & 3)) << 4)));
        }
#pragma unroll
        for (int i = 0; i < 4; ++i)
#pragma unroll
            for (int j = 0; j < 4; ++j)
                acc[i][j] = __builtin_amdgcn_mfma_f32_16x16x32_bf16(af[i], bfr[j], acc[i][j], 0, 0, 0);
    }
#pragma unroll
    for (int i = 0; i < 4; ++i) {
#pragma unroll
        for (int r = 0; r < 4; ++r) {
            size_t grow = (size_t)mt * 128 + wr + 16 * i + (l4 << 2) + r;
#pragma unroll
            for (int j = 0; j < 4; ++j) {
                int gcol = nt * 128 + wc + 16 * j + l15;
                Y[grow * 512 + gcol] = x[grow * 512 + gcol] + acc[i][j][r] + bo[gcol];
            }
        }
    }
}

// ---------------- in-place LayerNorm over rows of 512 ----------------
__global__ void k_ln(float* __restrict__ Y, const float* __restrict__ gamma,
                     const float* __restrict__ beta, float* __restrict__ out) {
    size_t row = blockIdx.x;
    int lane = threadIdx.x;
    float* y = Y + row * 512;
    float4 v0 = *(const float4*)(y + lane * 8);
    float4 v1 = *(const float4*)(y + lane * 8 + 4);
    float s = v0.x + v0.y + v0.z + v0.w + v1.x + v1.y + v1.z + v1.w;
    float q = v0.x * v0.x + v0.y * v0.y + v0.z * v0.z + v0.w * v0.w +
              v1.x * v1.x + v1.y * v1.y + v1.z * v1.z + v1.w * v1.w;
#pragma unroll
    for (int off = 1; off < 64; off <<= 1) {
        s += __shfl_xor(s, off);
        q += __shfl_xor(q, off);
    }
    float mu = s * (1.f / 512.f);
    float var = q * (1.f / 512.f) - mu * mu;
    float rsd = rsqrtf(var + 1e-5f);
    float o[8] = {v0.x, v0.y, v0.z, v0.w, v1.x, v1.y, v1.z, v1.w};
#pragma unroll
    for (int k = 0; k < 8; ++k) {
        int c = lane * 8 + k;
        o[k] = (o[k] - mu) * rsd * gamma[c] + beta[c];
    }
    *(float4*)(out + row * 512 + lane * 8)     = (float4){o[0], o[1], o[2], o[3]};
    *(float4*)(out + row * 512 + lane * 8 + 4) = (float4){o[4], o[5], o[6], o[7]};
}

extern "C" void kernel_launch(void* const* d_in, const int* in_sizes, int n_in,
                              void* d_out, int out_size, void* d_ws, size_t ws_size,
                              hipStream_t stream) {
    const float* x     = (const float*)d_in[0];
    const int*   adj   = (const int*)d_in[1];
    const float* Wq    = (const float*)d_in[2];
    const float* Wk    = (const float*)d_in[3];
    const float* Wv    = (const float*)d_in[4];
    const float* Wo    = (const float*)d_in[5];
    const float* bo    = (const float*)d_in[6];
    const float* gamma = (const float*)d_in[7];
    const float* beta  = (const float*)d_in[8];
    float* out = (float*)d_out;

    char* ws = (char*)d_ws;
    const size_t SZ_ROWS = (size_t)NBAT * LSEQ;           // 16384
    __hip_bfloat16* xb    = (__hip_bfloat16*)(ws);                       // 16.78 MB (reused as attn-out)
    __hip_bfloat16* Wtqkv = (__hip_bfloat16*)(ws + 16777216);            // 1.57 MB
    __hip_bfloat16* Wto   = (__hip_bfloat16*)(ws + 16777216 + 1572864);  // 0.52 MB
    __hip_bfloat16* Qb    = (__hip_bfloat16*)(ws + 18874368);            // 16.78 MB
    __hip_bfloat16* Kb    = (__hip_bfloat16*)(ws + 18874368 + 16777216);
    __hip_bfloat16* Vtb   = (__hip_bfloat16*)(ws + 18874368 + 2 * 16777216);
    __hip_bfloat16* Ab    = xb;  // attention output aliases xb (xb dead after QKV GEMM)
    (void)in_sizes; (void)n_in; (void)out_size; (void)ws_size;

    k_cvt_x<<<(SZ_ROWS * DDIM) / (256 * 4), 256, 0, stream>>>(x, xb);
    k_cvt_w<<<1024, 256, 0, stream>>>(Wq, Wk, Wv, Wo, Wtqkv, Wto);
    k_gemm_qkv<<<dim3(128, 12), 256, 0, stream>>>(xb, Wtqkv, Qb, Kb, Vtb);
    k_attn<<<256, 256, 0, stream>>>(Qb, Kb, Vtb, adj, Ab);
    k_gemm_out<<<dim3(128, 4), 256, 0, stream>>>(Ab, Wto, x, bo, out);
    k_ln<<<(unsigned)SZ_ROWS, 64, 0, stream>>>(out, gamma, beta, out);
}

// Round 3
// 596.336 us; speedup vs baseline: 1.0221x; 1.0221x over previous
//
#include <hip/hip_runtime.h>
#include <hip/hip_bf16.h>

typedef short bf16x8 __attribute__((ext_vector_type(8)));
typedef float f32x4  __attribute__((ext_vector_type(4)));

#define LSEQ 2048
#define DDIM 512
#define NBAT 8

// ---------------- convert x fp32 -> bf16 ----------------
__global__ void k_cvt_x(const float* __restrict__ x, __hip_bfloat16* __restrict__ xb) {
    size_t i = ((size_t)blockIdx.x * 256 + threadIdx.x) * 4;
    float4 v = *(const float4*)(x + i);
    __hip_bfloat16 h[4] = { __float2bfloat16(v.x), __float2bfloat16(v.y),
                            __float2bfloat16(v.z), __float2bfloat16(v.w) };
    *(short4*)(xb + i) = *(short4*)h;
}

// ---------------- convert + transpose weights ----------------
__global__ void k_cvt_w(const float* __restrict__ Wq, const float* __restrict__ Wk,
                        const float* __restrict__ Wv, const float* __restrict__ Wo,
                        __hip_bfloat16* __restrict__ Wtqkv, __hip_bfloat16* __restrict__ Wto) {
    __shared__ float t[32][33];
    int mat = blockIdx.x >> 8;
    int tb  = blockIdx.x & 255;
    int tk  = tb >> 4, tn = tb & 15;
    const float* W = (mat == 0) ? Wq : (mat == 1) ? Wk : (mat == 2) ? Wv : Wo;
    int c  = threadIdx.x & 31;
    int r0 = threadIdx.x >> 5;
#pragma unroll
    for (int i = 0; i < 4; ++i) {
        int r = r0 + i * 8;
        t[r][c] = W[(size_t)(tk * 32 + r) * 512 + tn * 32 + c];
    }
    __syncthreads();
    __hip_bfloat16* dst = (mat < 3) ? (Wtqkv + (size_t)mat * 512 * 512) : Wto;
#pragma unroll
    for (int i = 0; i < 4; ++i) {
        int n = r0 + i * 8;
        dst[(size_t)(tn * 32 + n) * 512 + tk * 32 + c] = __float2bfloat16(t[c][n]);
    }
}

// ---------------- fused QKV GEMM: C = xb @ [Wq|Wk|Wv]  (Bt form) ----------------
__global__ __launch_bounds__(256, 2)
void k_gemm_qkv(const __hip_bfloat16* __restrict__ A, const __hip_bfloat16* __restrict__ Bt,
                __hip_bfloat16* __restrict__ Q, __hip_bfloat16* __restrict__ Kb,
                __hip_bfloat16* __restrict__ Vt) {
    __shared__ char As[8192], Bs[8192];
    const int tid = threadIdx.x, lane = tid & 63, w = tid >> 6;
    const int l15 = lane & 15, l4 = lane >> 4;
    const int mt = blockIdx.x, nt = blockIdx.y;
    const int wr = (w >> 1) * 64, wc = (w & 1) * 64;
    f32x4 acc[4][4] = {};
    const int c0 = tid, c1 = tid + 256;
    const int r0 = c0 >> 2, o0 = c0 & 3, r1 = c1 >> 2, o1 = c1 & 3;

#pragma unroll 1
    for (int kt = 0; kt < 16; ++kt) {
        __syncthreads();
        bf16x8 a0 = *(const bf16x8*)(A + (size_t)(mt * 128 + r0) * 512 + kt * 32 + o0 * 8);
        bf16x8 a1 = *(const bf16x8*)(A + (size_t)(mt * 128 + r1) * 512 + kt * 32 + o1 * 8);
        bf16x8 b0 = *(const bf16x8*)(Bt + (size_t)(nt * 128 + r0) * 512 + kt * 32 + o0 * 8);
        bf16x8 b1 = *(const bf16x8*)(Bt + (size_t)(nt * 128 + r1) * 512 + kt * 32 + o1 * 8);
        *(bf16x8*)(As + r0 * 64 + ((o0 * 16) ^ ((((r0 >> 1) & 3)) << 4))) = a0;
        *(bf16x8*)(As + r1 * 64 + ((o1 * 16) ^ ((((r1 >> 1) & 3)) << 4))) = a1;
        *(bf16x8*)(Bs + r0 * 64 + ((o0 * 16) ^ ((((r0 >> 1) & 3)) << 4))) = b0;
        *(bf16x8*)(Bs + r1 * 64 + ((o1 * 16) ^ ((((r1 >> 1) & 3)) << 4))) = b1;
        __syncthreads();
        bf16x8 af[4], bfr[4];
#pragma unroll
        for (int i = 0; i < 4; ++i) {
            int r = wr + 16 * i + l15;
            af[i] = *(const bf16x8*)(As + r * 64 + ((16 * l4) ^ ((((r >> 1) & 3)) << 4)));
        }
#pragma unroll
        for (int j = 0; j < 4; ++j) {
            int r = wc + 16 * j + l15;
            bfr[j] = *(const bf16x8*)(Bs + r * 64 + ((16 * l4) ^ ((((r >> 1) & 3)) << 4)));
        }
#pragma unroll
        for (int i = 0; i < 4; ++i)
#pragma unroll
            for (int j = 0; j < 4; ++j)
                acc[i][j] = __builtin_amdgcn_mfma_f32_16x16x32_bf16(af[i], bfr[j], acc[i][j], 0, 0, 0);
    }
    const int which = (nt * 128) >> 9;  // uniform per block (0=q,1=k,2=v)
#pragma unroll
    for (int i = 0; i < 4; ++i) {
#pragma unroll
        for (int r = 0; r < 4; ++r) {
            int grow = mt * 128 + wr + 16 * i + (l4 << 2) + r;
#pragma unroll
            for (int j = 0; j < 4; ++j) {
                int gcol = nt * 128 + wc + 16 * j + l15;
                int cc = gcol & 511;
                __hip_bfloat16 h = __float2bfloat16(acc[i][j][r]);
                if (which == 0)      Q [(size_t)grow * 512 + cc] = h;
                else if (which == 1) Kb[(size_t)grow * 512 + cc] = h;
                else {
                    int b = grow >> 11, m = grow & 2047;
                    Vt[((size_t)b * 512 + cc) * 2048 + m] = h;
                }
            }
        }
    }
}

// ---------------- flash attention, KV-split x2 (grid 512 = 2 blocks/CU) ----------------
// blk: b = blk&7 (XCD affinity), s = (blk>>3)&1 (kv half), qt = blk>>4 (0..31).
// 4 waves x 16 q-rows, KVB=32, 32 kt iterations over 1024 keys.
// Writes UNNORMALIZED partial O (bf16) + per-row (m,l) for the combine pass.
__global__ __launch_bounds__(256, 1)
void k_attn(const __hip_bfloat16* __restrict__ Q, const __hip_bfloat16* __restrict__ Kg,
            const __hip_bfloat16* __restrict__ Vt, const int* __restrict__ adj,
            __hip_bfloat16* __restrict__ P0, __hip_bfloat16* __restrict__ P1,
            float* __restrict__ mlb) {
    __shared__ __hip_bfloat16 Kl[32][520];    // 33,280 B
    __shared__ __hip_bfloat16 Vl[512][40];    // 40,960 B
    __shared__ __hip_bfloat16 Pl[4][16][40];  //  5,120 B  => 79,360 B total
    const int tid = threadIdx.x, lane = tid & 63, w = tid >> 6;
    const int l15 = lane & 15, l4 = lane >> 4;
    const int b = blockIdx.x & 7, s = (blockIdx.x >> 3) & 1, qt = blockIdx.x >> 4;
    const float scale = 0.04419417382415922f;  // 1/sqrt(512)
    __hip_bfloat16* __restrict__ Op = s ? P1 : P0;

    // Q fragments in registers: wave's 16 rows x 512 k
    bf16x8 qf[16];
    {
        const __hip_bfloat16* qp = Q + ((size_t)b * LSEQ + qt * 64 + w * 16 + l15) * 512;
#pragma unroll
        for (int ks = 0; ks < 16; ++ks)
            qf[ks] = *(const bf16x8*)(qp + ks * 32 + l4 * 8);
    }
    f32x4 acc[32];
#pragma unroll
    for (int n = 0; n < 32; ++n) acc[n] = (f32x4){0.f, 0.f, 0.f, 0.f};
    float m_[4] = {-1e30f, -1e30f, -1e30f, -1e30f};
    float l_[4] = {0.f, 0.f, 0.f, 0.f};

#pragma unroll 1
    for (int kt = 0; kt < 32; ++kt) {
        __syncthreads();
        // stage K tile (32 rows x 512 k) for keys [s*1024 + kt*32 ...)
        {
            const __hip_bfloat16* kp = Kg + ((size_t)b * LSEQ + s * 1024 + kt * 32) * 512;
#pragma unroll
            for (int i = 0; i < 8; ++i) {
                int c = tid + i * 256;
                int r = c >> 6, o = c & 63;
                bf16x8 v = *(const bf16x8*)(kp + (size_t)r * 512 + o * 8);
                *(bf16x8*)(&Kl[r][o * 8]) = v;
            }
        }
        // stage V tile (512 d-rows x 32 m) from Vt
        {
            const __hip_bfloat16* vp = Vt + (size_t)b * 512 * 2048 + s * 1024 + kt * 32;
#pragma unroll
            for (int i = 0; i < 8; ++i) {
                int c = tid + i * 256;
                int r = c >> 2, o = c & 3;
                bf16x8 v = *(const bf16x8*)(vp + (size_t)r * 2048 + o * 8);
                *(bf16x8*)(&Vl[r][o * 8]) = v;
            }
        }
        // adj bits for this wave's 16 rows x 32 cols
        unsigned amask = 0;
        {
            const int* ap = adj + ((size_t)b * LSEQ + qt * 64 + w * 16 + l4 * 4) * LSEQ
                          + s * 1024 + kt * 32 + l15;
#pragma unroll
            for (int r = 0; r < 4; ++r)
#pragma unroll
                for (int n = 0; n < 2; ++n) {
                    int a = ap[(size_t)r * LSEQ + n * 16];
                    amask |= (a != 0 ? 1u : 0u) << (n * 4 + r);
                }
        }
        __syncthreads();
        // scores: S = Q . K^T for wave's 16 rows x 32 keys
        f32x4 sa[2];
#pragma unroll
        for (int n = 0; n < 2; ++n) sa[n] = (f32x4){0.f, 0.f, 0.f, 0.f};
        __builtin_amdgcn_s_setprio(1);
#pragma unroll
        for (int ks = 0; ks < 16; ++ks) {
#pragma unroll
            for (int n = 0; n < 2; ++n) {
                bf16x8 bk = *(const bf16x8*)(&Kl[n * 16 + l15][ks * 32 + l4 * 8]);
                sa[n] = __builtin_amdgcn_mfma_f32_16x16x32_bf16(qf[ks], bk, sa[n], 0, 0, 0);
            }
        }
        __builtin_amdgcn_s_setprio(0);
        // masked row max (across the 16-lane group)
        float mx[4];
#pragma unroll
        for (int r = 0; r < 4; ++r) {
            float v = -1e30f;
#pragma unroll
            for (int n = 0; n < 2; ++n)
                if ((amask >> (n * 4 + r)) & 1) v = fmaxf(v, sa[n][r] * scale);
            v = fmaxf(v, __shfl_xor(v, 1));
            v = fmaxf(v, __shfl_xor(v, 2));
            v = fmaxf(v, __shfl_xor(v, 4));
            v = fmaxf(v, __shfl_xor(v, 8));
            mx[r] = v;
        }
        // deferred-max online softmax update (THR=8)
        float rs[4];
        bool need = false;
#pragma unroll
        for (int r = 0; r < 4; ++r) {
            rs[r] = 1.f;
            if (mx[r] > m_[r] + 8.f) { rs[r] = __expf(m_[r] - mx[r]); m_[r] = mx[r]; }
            l_[r] *= rs[r];
            need |= (rs[r] != 1.f);
        }
        if (need) {
#pragma unroll
            for (int n = 0; n < 32; ++n) {
                acc[n][0] *= rs[0]; acc[n][1] *= rs[1];
                acc[n][2] *= rs[2]; acc[n][3] *= rs[3];
            }
        }
        // p = exp(s - m) (masked -> 0); row sums
#pragma unroll
        for (int n = 0; n < 2; ++n)
#pragma unroll
            for (int r = 0; r < 4; ++r) {
                float p = ((amask >> (n * 4 + r)) & 1) ? __expf(sa[n][r] * scale - m_[r]) : 0.f;
                sa[n][r] = p;
            }
#pragma unroll
        for (int r = 0; r < 4; ++r) {
            float sm = sa[0][r] + sa[1][r];
            sm += __shfl_xor(sm, 1);
            sm += __shfl_xor(sm, 2);
            sm += __shfl_xor(sm, 4);
            sm += __shfl_xor(sm, 8);
            l_[r] += sm;
        }
        // relayout P via per-wave LDS into A-frags
#pragma unroll
        for (int n = 0; n < 2; ++n)
#pragma unroll
            for (int r = 0; r < 4; ++r)
                Pl[w][l4 * 4 + r][n * 16 + l15] = __float2bfloat16(sa[n][r]);
        // PV accumulate: acc += P @ V  (Bt form via Vl), single K-step of 32
        {
            bf16x8 pf = *(const bf16x8*)(&Pl[w][l15][l4 * 8]);
            __builtin_amdgcn_s_setprio(1);
#pragma unroll
            for (int n = 0; n < 32; ++n) {
                bf16x8 bv = *(const bf16x8*)(&Vl[n * 16 + l15][l4 * 8]);
                acc[n] = __builtin_amdgcn_mfma_f32_16x16x32_bf16(pf, bv, acc[n], 0, 0, 0);
            }
            __builtin_amdgcn_s_setprio(0);
        }
    }
    // epilogue: store raw (unnormalized) partials + (m,l) per row
#pragma unroll
    for (int r = 0; r < 4; ++r) {
        size_t row = (size_t)b * LSEQ + qt * 64 + w * 16 + l4 * 4 + r;
#pragma unroll
        for (int n = 0; n < 32; ++n)
            Op[row * 512 + n * 16 + l15] = __float2bfloat16(acc[n][r]);
        if (l15 == 0) {
            mlb[((size_t)s * 16384 + row) * 2 + 0] = m_[r];
            mlb[((size_t)s * 16384 + row) * 2 + 1] = l_[r];
        }
    }
}

// ---------------- combine the two KV-split partials (exact LSE merge) ----------------
// NOTE: outp may alias p0 (element-wise read-then-write by the same thread).
__global__ void k_combine(const __hip_bfloat16* p0, const __hip_bfloat16* __restrict__ p1,
                          const float* __restrict__ mlb, __hip_bfloat16* outp) {
    size_t idx = (size_t)blockIdx.x * 256 + threadIdx.x;  // one thread = 8 elems
    size_t row = idx >> 6;
    int    c8  = (int)(idx & 63) * 8;
    float m0 = mlb[row * 2 + 0],             l0 = mlb[row * 2 + 1];
    float m1 = mlb[(16384 + row) * 2 + 0],   l1 = mlb[(16384 + row) * 2 + 1];
    float M  = fmaxf(m0, m1);
    float e0 = __expf(m0 - M), e1 = __expf(m1 - M);
    float den = l0 * e0 + l1 * e1;
    float inv = (den > 0.f) ? 1.f / den : 0.f;
    bf16x8 a = *(const bf16x8*)(p0 + row * 512 + c8);
    bf16x8 c = *(const bf16x8*)(p1 + row * 512 + c8);
    __hip_bfloat16 o[8];
#pragma unroll
    for (int k = 0; k < 8; ++k) {
        float fa = __bfloat162float(*(const __hip_bfloat16*)&((short*)&a)[k]);
        float fc = __bfloat162float(*(const __hip_bfloat16*)&((short*)&c)[k]);
        o[k] = __float2bfloat16((fa * e0 + fc * e1) * inv);
    }
    *(bf16x8*)(outp + row * 512 + c8) = *(bf16x8*)o;
}

// ---------------- out projection + residual + bias -> Y fp32 (into d_out) ----------------
__global__ __launch_bounds__(256, 2)
void k_gemm_out(const __hip_bfloat16* __restrict__ A, const __hip_bfloat16* __restrict__ Bt,
                const float* __restrict__ x, const float* __restrict__ bo,
                float* __restrict__ Y) {
    __shared__ char As[8192], Bs[8192];
    const int tid = threadIdx.x, lane = tid & 63, w = tid >> 6;
    const int l15 = lane & 15, l4 = lane >> 4;
    const int mt = blockIdx.x, nt = blockIdx.y;
    const int wr = (w >> 1) * 64, wc = (w & 1) * 64;
    f32x4 acc[4][4] = {};
    const int c0 = tid, c1 = tid + 256;
    const int r0 = c0 >> 2, o0 = c0 & 3, r1 = c1 >> 2, o1 = c1 & 3;

#pragma unroll 1
    for (int kt = 0; kt < 16; ++kt) {
        __syncthreads();
        bf16x8 a0 = *(const bf16x8*)(A + (size_t)(mt * 128 + r0) * 512 + kt * 32 + o0 * 8);
        bf16x8 a1 = *(const bf16x8*)(A + (size_t)(mt * 128 + r1) * 512 + kt * 32 + o1 * 8);
        bf16x8 b0 = *(const bf16x8*)(Bt + (size_t)(nt * 128 + r0) * 512 + kt * 32 + o0 * 8);
        bf16x8 b1 = *(const bf16x8*)(Bt + (size_t)(nt * 128 + r1) * 512 + kt * 32 + o1 * 8);
        *(bf16x8*)(As + r0 * 64 + ((o0 * 16) ^ ((((r0 >> 1) & 3)) << 4))) = a0;
        *(bf16x8*)(As + r1 * 64 + ((o1 * 16) ^ ((((r1 >> 1) & 3)) << 4))) = a1;
        *(bf16x8*)(Bs + r0 * 64 + ((o0 * 16) ^ ((((r0 >> 1) & 3)) << 4))) = b0;
        *(bf16x8*)(Bs + r1 * 64 + ((o1 * 16) ^ ((((r1 >> 1) & 3)) << 4))) = b1;
        __syncthreads();
        bf16x8 af[4], bfr[4];
#pragma unroll
        for (int i = 0; i < 4; ++i) {
            int r = wr + 16 * i + l15;
            af[i] = *(const bf16x8*)(As + r * 64 + ((16 * l4) ^ ((((r >> 1) & 3)) << 4)));
        }
#pragma unroll
        for (int j = 0; j < 4; ++j) {
            int r = wc + 16 * j + l15;
            bfr[j] = *(const bf16x8*)(Bs + r * 64 + ((16 * l4) ^ ((((r >> 1) & 3)) << 4)));
        }
#pragma unroll
        for (int i = 0; i < 4; ++i)
#pragma unroll
            for (int j = 0; j < 4; ++j)
                acc[i][j] = __builtin_amdgcn_mfma_f32_16x16x32_bf16(af[i], bfr[j], acc[i][j], 0, 0, 0);
    }
#pragma unroll
    for (int i = 0; i < 4; ++i) {
#pragma unroll
        for (int r = 0; r < 4; ++r) {
            size_t grow = (size_t)mt * 128 + wr + 16 * i + (l4 << 2) + r;
#pragma unroll
            for (int j = 0; j < 4; ++j) {
                int gcol = nt * 128 + wc + 16 * j + l15;
                Y[grow * 512 + gcol] = x[grow * 512 + gcol] + acc[i][j][r] + bo[gcol];
            }
        }
    }
}

// ---------------- in-place LayerNorm over rows of 512 ----------------
__global__ void k_ln(float* __restrict__ Y, const float* __restrict__ gamma,
                     const float* __restrict__ beta, float* __restrict__ out) {
    size_t row = blockIdx.x;
    int lane = threadIdx.x;
    float* y = Y + row * 512;
    float4 v0 = *(const float4*)(y + lane * 8);
    float4 v1 = *(const float4*)(y + lane * 8 + 4);
    float s = v0.x + v0.y + v0.z + v0.w + v1.x + v1.y + v1.z + v1.w;
    float q = v0.x * v0.x + v0.y * v0.y + v0.z * v0.z + v0.w * v0.w +
              v1.x * v1.x + v1.y * v1.y + v1.z * v1.z + v1.w * v1.w;
#pragma unroll
    for (int off = 1; off < 64; off <<= 1) {
        s += __shfl_xor(s, off);
        q += __shfl_xor(q, off);
    }
    float mu = s * (1.f / 512.f);
    float var = q * (1.f / 512.f) - mu * mu;
    float rsd = rsqrtf(var + 1e-5f);
    float o[8] = {v0.x, v0.y, v0.z, v0.w, v1.x, v1.y, v1.z, v1.w};
#pragma unroll
    for (int k = 0; k < 8; ++k) {
        int c = lane * 8 + k;
        o[k] = (o[k] - mu) * rsd * gamma[c] + beta[c];
    }
    *(float4*)(out + row * 512 + lane * 8)     = (float4){o[0], o[1], o[2], o[3]};
    *(float4*)(out + row * 512 + lane * 8 + 4) = (float4){o[4], o[5], o[6], o[7]};
}

extern "C" void kernel_launch(void* const* d_in, const int* in_sizes, int n_in,
                              void* d_out, int out_size, void* d_ws, size_t ws_size,
                              hipStream_t stream) {
    const float* x     = (const float*)d_in[0];
    const int*   adj   = (const int*)d_in[1];
    const float* Wq    = (const float*)d_in[2];
    const float* Wk    = (const float*)d_in[3];
    const float* Wv    = (const float*)d_in[4];
    const float* Wo    = (const float*)d_in[5];
    const float* bo    = (const float*)d_in[6];
    const float* gamma = (const float*)d_in[7];
    const float* beta  = (const float*)d_in[8];
    float* out = (float*)d_out;

    char* ws = (char*)d_ws;
    const size_t SZ_ROWS = (size_t)NBAT * LSEQ;  // 16384
    __hip_bfloat16* xb    = (__hip_bfloat16*)(ws);              // 16.78 MB; later = partial0 = attn-out
    __hip_bfloat16* Wtqkv = (__hip_bfloat16*)(ws + 16777216);   // 1.57 MB
    __hip_bfloat16* Wto   = (__hip_bfloat16*)(ws + 18350080);   // 0.52 MB
    __hip_bfloat16* Qb    = (__hip_bfloat16*)(ws + 18874368);   // 16.78 MB
    __hip_bfloat16* Kb    = (__hip_bfloat16*)(ws + 35651584);   // 16.78 MB
    __hip_bfloat16* Vtb   = (__hip_bfloat16*)(ws + 52428800);   // 16.78 MB
    __hip_bfloat16* P1    = (__hip_bfloat16*)(ws + 69206016);   // 16.78 MB (partial1)
    float*          mlb   = (float*)        (ws + 85983232);    // 0.26 MB  (m,l per split/row)
    __hip_bfloat16* P0    = xb;   // partial0 / final attn-out alias
    __hip_bfloat16* Ab    = xb;
    (void)in_sizes; (void)n_in; (void)out_size; (void)ws_size;

    k_cvt_x<<<(SZ_ROWS * DDIM) / (256 * 4), 256, 0, stream>>>(x, xb);
    k_cvt_w<<<1024, 256, 0, stream>>>(Wq, Wk, Wv, Wo, Wtqkv, Wto);
    k_gemm_qkv<<<dim3(128, 12), 256, 0, stream>>>(xb, Wtqkv, Qb, Kb, Vtb);
    k_attn<<<512, 256, 0, stream>>>(Qb, Kb, Vtb, adj, P0, P1, mlb);
    k_combine<<<4096, 256, 0, stream>>>(P0, P1, mlb, Ab);
    k_gemm_out<<<dim3(128, 4), 256, 0, stream>>>(Ab, Wto, x, bo, out);
    k_ln<<<(unsigned)SZ_ROWS, 64, 0, stream>>>(out, gamma, beta, out);
}

// Round 4
// 375.303 us; speedup vs baseline: 1.6241x; 1.5889x over previous
//
#include <hip/hip_runtime.h>
#include <hip/hip_bf16.h>

typedef short bf16x8 __attribute__((ext_vector_type(8)));
typedef float f32x4  __attribute__((ext_vector_type(4)));

#define LSEQ 2048
#define DDIM 512
#define NBAT 8

// ---------------- convert x fp32 -> bf16 ----------------
__global__ void k_cvt_x(const float* __restrict__ x, __hip_bfloat16* __restrict__ xb) {
    size_t i = ((size_t)blockIdx.x * 256 + threadIdx.x) * 4;
    float4 v = *(const float4*)(x + i);
    __hip_bfloat16 h[4] = { __float2bfloat16(v.x), __float2bfloat16(v.y),
                            __float2bfloat16(v.z), __float2bfloat16(v.w) };
    *(short4*)(xb + i) = *(short4*)h;
}

// ---------------- convert + transpose weights ----------------
__global__ void k_cvt_w(const float* __restrict__ Wq, const float* __restrict__ Wk,
                        const float* __restrict__ Wv, const float* __restrict__ Wo,
                        __hip_bfloat16* __restrict__ Wtqkv, __hip_bfloat16* __restrict__ Wto) {
    __shared__ float t[32][33];
    int mat = blockIdx.x >> 8;
    int tb  = blockIdx.x & 255;
    int tk  = tb >> 4, tn = tb & 15;
    const float* W = (mat == 0) ? Wq : (mat == 1) ? Wk : (mat == 2) ? Wv : Wo;
    int c  = threadIdx.x & 31;
    int r0 = threadIdx.x >> 5;
#pragma unroll
    for (int i = 0; i < 4; ++i) {
        int r = r0 + i * 8;
        t[r][c] = W[(size_t)(tk * 32 + r) * 512 + tn * 32 + c];
    }
    __syncthreads();
    __hip_bfloat16* dst = (mat < 3) ? (Wtqkv + (size_t)mat * 512 * 512) : Wto;
#pragma unroll
    for (int i = 0; i < 4; ++i) {
        int n = r0 + i * 8;
        dst[(size_t)(tn * 32 + n) * 512 + tk * 32 + c] = __float2bfloat16(t[c][n]);
    }
}

// ---------------- fused QKV GEMM: C = xb @ [Wq|Wk|Wv]  (Bt form) ----------------
__global__ __launch_bounds__(256, 2)
void k_gemm_qkv(const __hip_bfloat16* __restrict__ A, const __hip_bfloat16* __restrict__ Bt,
                __hip_bfloat16* __restrict__ Q, __hip_bfloat16* __restrict__ Kb,
                __hip_bfloat16* __restrict__ Vt) {
    __shared__ char As[8192], Bs[8192];
    const int tid = threadIdx.x, lane = tid & 63, w = tid >> 6;
    const int l15 = lane & 15, l4 = lane >> 4;
    const int mt = blockIdx.x, nt = blockIdx.y;
    const int wr = (w >> 1) * 64, wc = (w & 1) * 64;
    f32x4 acc[4][4] = {};
    const int c0 = tid, c1 = tid + 256;
    const int r0 = c0 >> 2, o0 = c0 & 3, r1 = c1 >> 2, o1 = c1 & 3;

#pragma unroll 1
    for (int kt = 0; kt < 16; ++kt) {
        __syncthreads();
        bf16x8 a0 = *(const bf16x8*)(A + (size_t)(mt * 128 + r0) * 512 + kt * 32 + o0 * 8);
        bf16x8 a1 = *(const bf16x8*)(A + (size_t)(mt * 128 + r1) * 512 + kt * 32 + o1 * 8);
        bf16x8 b0 = *(const bf16x8*)(Bt + (size_t)(nt * 128 + r0) * 512 + kt * 32 + o0 * 8);
        bf16x8 b1 = *(const bf16x8*)(Bt + (size_t)(nt * 128 + r1) * 512 + kt * 32 + o1 * 8);
        *(bf16x8*)(As + r0 * 64 + ((o0 * 16) ^ ((((r0 >> 1) & 3)) << 4))) = a0;
        *(bf16x8*)(As + r1 * 64 + ((o1 * 16) ^ ((((r1 >> 1) & 3)) << 4))) = a1;
        *(bf16x8*)(Bs + r0 * 64 + ((o0 * 16) ^ ((((r0 >> 1) & 3)) << 4))) = b0;
        *(bf16x8*)(Bs + r1 * 64 + ((o1 * 16) ^ ((((r1 >> 1) & 3)) << 4))) = b1;
        __syncthreads();
        bf16x8 af[4], bfr[4];
#pragma unroll
        for (int i = 0; i < 4; ++i) {
            int r = wr + 16 * i + l15;
            af[i] = *(const bf16x8*)(As + r * 64 + ((16 * l4) ^ ((((r >> 1) & 3)) << 4)));
        }
#pragma unroll
        for (int j = 0; j < 4; ++j) {
            int r = wc + 16 * j + l15;
            bfr[j] = *(const bf16x8*)(Bs + r * 64 + ((16 * l4) ^ ((((r >> 1) & 3)) << 4)));
        }
#pragma unroll
        for (int i = 0; i < 4; ++i)
#pragma unroll
            for (int j = 0; j < 4; ++j)
                acc[i][j] = __builtin_amdgcn_mfma_f32_16x16x32_bf16(af[i], bfr[j], acc[i][j], 0, 0, 0);
    }
    const int which = (nt * 128) >> 9;  // uniform per block (0=q,1=k,2=v)
#pragma unroll
    for (int i = 0; i < 4; ++i) {
#pragma unroll
        for (int r = 0; r < 4; ++r) {
            int grow = mt * 128 + wr + 16 * i + (l4 << 2) + r;
#pragma unroll
            for (int j = 0; j < 4; ++j) {
                int gcol = nt * 128 + wc + 16 * j + l15;
                int cc = gcol & 511;
                __hip_bfloat16 h = __float2bfloat16(acc[i][j][r]);
                if (which == 0)      Q [(size_t)grow * 512 + cc] = h;
                else if (which == 1) Kb[(size_t)grow * 512 + cc] = h;
                else {
                    int b = grow >> 11, m = grow & 2047;
                    Vt[((size_t)b * 512 + cc) * 2048 + m] = h;
                }
            }
        }
    }
}

// ---------------- flash attention: 8 waves/block, KV-split x2 across blocks ----------------
// grid 256 (1 block/CU, 2 waves/SIMD): b = blk&7 (XCD), qt = (blk>>3)&15 (128 q-rows), s = blk>>7.
// All 8 waves share one K/V tile (KVB=64, 16 iters over 1024 keys); wave w owns 16 q-rows.
// Writes UNNORMALIZED partial O (bf16) + per-row (m,l) for the combine pass.
__global__ __launch_bounds__(512, 2)
void k_attn(const __hip_bfloat16* __restrict__ Q, const __hip_bfloat16* __restrict__ Kg,
            const __hip_bfloat16* __restrict__ Vt, const int* __restrict__ adj,
            __hip_bfloat16* __restrict__ P0, __hip_bfloat16* __restrict__ P1,
            float* __restrict__ mlb) {
    __shared__ __hip_bfloat16 Kl[64][520];    // 66,560 B
    __shared__ __hip_bfloat16 Vl[512][72];    // 73,728 B
    __shared__ __hip_bfloat16 Pl[8][16][72];  // 18,432 B  => 158,720 B total
    const int tid = threadIdx.x, lane = tid & 63, w = tid >> 6;
    const int l15 = lane & 15, l4 = lane >> 4;
    const int b = blockIdx.x & 7, qt = (blockIdx.x >> 3) & 15, s = blockIdx.x >> 7;
    const float scale = 0.04419417382415922f;  // 1/sqrt(512)
    __hip_bfloat16* __restrict__ Op = s ? P1 : P0;

    // Q fragments in registers: wave's 16 rows x 512 k
    bf16x8 qf[16];
    {
        const __hip_bfloat16* qp = Q + ((size_t)b * LSEQ + qt * 128 + w * 16 + l15) * 512;
#pragma unroll
        for (int ks = 0; ks < 16; ++ks)
            qf[ks] = *(const bf16x8*)(qp + ks * 32 + l4 * 8);
    }
    f32x4 acc[32];
#pragma unroll
    for (int n = 0; n < 32; ++n) acc[n] = (f32x4){0.f, 0.f, 0.f, 0.f};
    float m_[4] = {-1e30f, -1e30f, -1e30f, -1e30f};
    float l_[4] = {0.f, 0.f, 0.f, 0.f};

#pragma unroll 1
    for (int kt = 0; kt < 16; ++kt) {
        __syncthreads();
        // stage K tile (64 rows x 512 k) for keys [s*1024 + kt*64 ...)
        {
            const __hip_bfloat16* kp = Kg + ((size_t)b * LSEQ + s * 1024 + kt * 64) * 512;
#pragma unroll
            for (int i = 0; i < 8; ++i) {
                int c = tid + i * 512;
                int r = c >> 6, o = c & 63;
                bf16x8 v = *(const bf16x8*)(kp + (size_t)r * 512 + o * 8);
                *(bf16x8*)(&Kl[r][o * 8]) = v;
            }
        }
        // stage V tile (512 d-rows x 64 m) from Vt
        {
            const __hip_bfloat16* vp = Vt + (size_t)b * 512 * 2048 + s * 1024 + kt * 64;
#pragma unroll
            for (int i = 0; i < 8; ++i) {
                int c = tid + i * 512;
                int r = c >> 3, o = c & 7;
                bf16x8 v = *(const bf16x8*)(vp + (size_t)r * 2048 + o * 8);
                *(bf16x8*)(&Vl[r][o * 8]) = v;
            }
        }
        // adj bits for this wave's 16 rows x 64 cols
        unsigned amask = 0;
        {
            const int* ap = adj + ((size_t)b * LSEQ + qt * 128 + w * 16 + l4 * 4) * LSEQ
                          + s * 1024 + kt * 64 + l15;
#pragma unroll
            for (int r = 0; r < 4; ++r)
#pragma unroll
                for (int n = 0; n < 4; ++n) {
                    int a = ap[(size_t)r * LSEQ + n * 16];
                    amask |= (a != 0 ? 1u : 0u) << (n * 4 + r);
                }
        }
        __syncthreads();
        // scores: S = Q . K^T for wave's 16 rows x 64 keys
        f32x4 sa[4];
#pragma unroll
        for (int n = 0; n < 4; ++n) sa[n] = (f32x4){0.f, 0.f, 0.f, 0.f};
        __builtin_amdgcn_s_setprio(1);
#pragma unroll
        for (int ks = 0; ks < 16; ++ks) {
#pragma unroll
            for (int n = 0; n < 4; ++n) {
                bf16x8 bk = *(const bf16x8*)(&Kl[n * 16 + l15][ks * 32 + l4 * 8]);
                sa[n] = __builtin_amdgcn_mfma_f32_16x16x32_bf16(qf[ks], bk, sa[n], 0, 0, 0);
            }
        }
        __builtin_amdgcn_s_setprio(0);
        // masked row max (across the 16-lane group)
        float mx[4];
#pragma unroll
        for (int r = 0; r < 4; ++r) {
            float v = -1e30f;
#pragma unroll
            for (int n = 0; n < 4; ++n)
                if ((amask >> (n * 4 + r)) & 1) v = fmaxf(v, sa[n][r] * scale);
            v = fmaxf(v, __shfl_xor(v, 1));
            v = fmaxf(v, __shfl_xor(v, 2));
            v = fmaxf(v, __shfl_xor(v, 4));
            v = fmaxf(v, __shfl_xor(v, 8));
            mx[r] = v;
        }
        // deferred-max online softmax update (THR=8)
        float rs[4];
        bool need = false;
#pragma unroll
        for (int r = 0; r < 4; ++r) {
            rs[r] = 1.f;
            if (mx[r] > m_[r] + 8.f) { rs[r] = __expf(m_[r] - mx[r]); m_[r] = mx[r]; }
            l_[r] *= rs[r];
            need |= (rs[r] != 1.f);
        }
        if (need) {
#pragma unroll
            for (int n = 0; n < 32; ++n) {
                acc[n][0] *= rs[0]; acc[n][1] *= rs[1];
                acc[n][2] *= rs[2]; acc[n][3] *= rs[3];
            }
        }
        // p = exp(s - m) (masked -> 0); row sums
#pragma unroll
        for (int n = 0; n < 4; ++n)
#pragma unroll
            for (int r = 0; r < 4; ++r) {
                float p = ((amask >> (n * 4 + r)) & 1) ? __expf(sa[n][r] * scale - m_[r]) : 0.f;
                sa[n][r] = p;
            }
#pragma unroll
        for (int r = 0; r < 4; ++r) {
            float sm = sa[0][r] + sa[1][r] + sa[2][r] + sa[3][r];
            sm += __shfl_xor(sm, 1);
            sm += __shfl_xor(sm, 2);
            sm += __shfl_xor(sm, 4);
            sm += __shfl_xor(sm, 8);
            l_[r] += sm;
        }
        // relayout P via per-wave LDS into A-frags
#pragma unroll
        for (int n = 0; n < 4; ++n)
#pragma unroll
            for (int r = 0; r < 4; ++r)
                Pl[w][l4 * 4 + r][n * 16 + l15] = __float2bfloat16(sa[n][r]);
        // PV accumulate: acc += P @ V  (Bt form via Vl), K-step 64 = 2 sub-steps
#pragma unroll
        for (int ks2 = 0; ks2 < 2; ++ks2) {
            bf16x8 pf = *(const bf16x8*)(&Pl[w][l15][ks2 * 32 + l4 * 8]);
            __builtin_amdgcn_s_setprio(1);
#pragma unroll
            for (int n = 0; n < 32; ++n) {
                bf16x8 bv = *(const bf16x8*)(&Vl[n * 16 + l15][ks2 * 32 + l4 * 8]);
                acc[n] = __builtin_amdgcn_mfma_f32_16x16x32_bf16(pf, bv, acc[n], 0, 0, 0);
            }
            __builtin_amdgcn_s_setprio(0);
        }
    }
    // epilogue: store raw (unnormalized) partials + (m,l) per row
#pragma unroll
    for (int r = 0; r < 4; ++r) {
        size_t row = (size_t)b * LSEQ + qt * 128 + w * 16 + l4 * 4 + r;
#pragma unroll
        for (int n = 0; n < 32; ++n)
            Op[row * 512 + n * 16 + l15] = __float2bfloat16(acc[n][r]);
        if (l15 == 0) {
            mlb[((size_t)s * 16384 + row) * 2 + 0] = m_[r];
            mlb[((size_t)s * 16384 + row) * 2 + 1] = l_[r];
        }
    }
}

// ---------------- combine the two KV-split partials (exact LSE merge) ----------------
// NOTE: outp may alias p0 (element-wise read-then-write by the same thread).
__global__ void k_combine(const __hip_bfloat16* p0, const __hip_bfloat16* __restrict__ p1,
                          const float* __restrict__ mlb, __hip_bfloat16* outp) {
    size_t idx = (size_t)blockIdx.x * 256 + threadIdx.x;  // one thread = 8 elems
    size_t row = idx >> 6;
    int    c8  = (int)(idx & 63) * 8;
    float m0 = mlb[row * 2 + 0],             l0 = mlb[row * 2 + 1];
    float m1 = mlb[(16384 + row) * 2 + 0],   l1 = mlb[(16384 + row) * 2 + 1];
    float M  = fmaxf(m0, m1);
    float e0 = __expf(m0 - M), e1 = __expf(m1 - M);
    float den = l0 * e0 + l1 * e1;
    float inv = (den > 0.f) ? 1.f / den : 0.f;
    bf16x8 a = *(const bf16x8*)(p0 + row * 512 + c8);
    bf16x8 c = *(const bf16x8*)(p1 + row * 512 + c8);
    __hip_bfloat16 o[8];
#pragma unroll
    for (int k = 0; k < 8; ++k) {
        float fa = __bfloat162float(*(const __hip_bfloat16*)&((short*)&a)[k]);
        float fc = __bfloat162float(*(const __hip_bfloat16*)&((short*)&c)[k]);
        o[k] = __float2bfloat16((fa * e0 + fc * e1) * inv);
    }
    *(bf16x8*)(outp + row * 512 + c8) = *(bf16x8*)o;
}

// ---------------- out projection + residual + bias -> Y fp32 (into d_out) ----------------
__global__ __launch_bounds__(256, 2)
void k_gemm_out(const __hip_bfloat16* __restrict__ A, const __hip_bfloat16* __restrict__ Bt,
                const float* __restrict__ x, const float* __restrict__ bo,
                float* __restrict__ Y) {
    __shared__ char As[8192], Bs[8192];
    const int tid = threadIdx.x, lane = tid & 63, w = tid >> 6;
    const int l15 = lane & 15, l4 = lane >> 4;
    const int mt = blockIdx.x, nt = blockIdx.y;
    const int wr = (w >> 1) * 64, wc = (w & 1) * 64;
    f32x4 acc[4][4] = {};
    const int c0 = tid, c1 = tid + 256;
    const int r0 = c0 >> 2, o0 = c0 & 3, r1 = c1 >> 2, o1 = c1 & 3;

#pragma unroll 1
    for (int kt = 0; kt < 16; ++kt) {
        __syncthreads();
        bf16x8 a0 = *(const bf16x8*)(A + (size_t)(mt * 128 + r0) * 512 + kt * 32 + o0 * 8);
        bf16x8 a1 = *(const bf16x8*)(A + (size_t)(mt * 128 + r1) * 512 + kt * 32 + o1 * 8);
        bf16x8 b0 = *(const bf16x8*)(Bt + (size_t)(nt * 128 + r0) * 512 + kt * 32 + o0 * 8);
        bf16x8 b1 = *(const bf16x8*)(Bt + (size_t)(nt * 128 + r1) * 512 + kt * 32 + o1 * 8);
        *(bf16x8*)(As + r0 * 64 + ((o0 * 16) ^ ((((r0 >> 1) & 3)) << 4))) = a0;
        *(bf16x8*)(As + r1 * 64 + ((o1 * 16) ^ ((((r1 >> 1) & 3)) << 4))) = a1;
        *(bf16x8*)(Bs + r0 * 64 + ((o0 * 16) ^ ((((r0 >> 1) & 3)) << 4))) = b0;
        *(bf16x8*)(Bs + r1 * 64 + ((o1 * 16) ^ ((((r1 >> 1) & 3)) << 4))) = b1;
        __syncthreads();
        bf16x8 af[4], bfr[4];
#pragma unroll
        for (int i = 0; i < 4; ++i) {
            int r = wr + 16 * i + l15;
            af[i] = *(const bf16x8*)(As + r * 64 + ((16 * l4) ^ ((((r >> 1) & 3)) << 4)));
        }
#pragma unroll
        for (int j = 0; j < 4; ++j) {
            int r = wc + 16 * j + l15;
            bfr[j] = *(const bf16x8*)(Bs + r * 64 + ((16 * l4) ^ ((((r >> 1) & 3)) << 4)));
        }
#pragma unroll
        for (int i = 0; i < 4; ++i)
#pragma unroll
            for (int j = 0; j < 4; ++j)
                acc[i][j] = __builtin_amdgcn_mfma_f32_16x16x32_bf16(af[i], bfr[j], acc[i][j], 0, 0, 0);
    }
#pragma unroll
    for (int i = 0; i < 4; ++i) {
#pragma unroll
        for (int r = 0; r < 4; ++r) {
            size_t grow = (size_t)mt * 128 + wr + 16 * i + (l4 << 2) + r;
#pragma unroll
            for (int j = 0; j < 4; ++j) {
                int gcol = nt * 128 + wc + 16 * j + l15;
                Y[grow * 512 + gcol] = x[grow * 512 + gcol] + acc[i][j][r] + bo[gcol];
            }
        }
    }
}

// ---------------- in-place LayerNorm over rows of 512 ----------------
__global__ void k_ln(float* __restrict__ Y, const float* __restrict__ gamma,
                     const float* __restrict__ beta, float* __restrict__ out) {
    size_t row = blockIdx.x;
    int lane = threadIdx.x;
    float* y = Y + row * 512;
    float4 v0 = *(const float4*)(y + lane * 8);
    float4 v1 = *(const float4*)(y + lane * 8 + 4);
    float s = v0.x + v0.y + v0.z + v0.w + v1.x + v1.y + v1.z + v1.w;
    float q = v0.x * v0.x + v0.y * v0.y + v0.z * v0.z + v0.w * v0.w +
              v1.x * v1.x + v1.y * v1.y + v1.z * v1.z + v1.w * v1.w;
#pragma unroll
    for (int off = 1; off < 64; off <<= 1) {
        s += __shfl_xor(s, off);
        q += __shfl_xor(q, off);
    }
    float mu = s * (1.f / 512.f);
    float var = q * (1.f / 512.f) - mu * mu;
    float rsd = rsqrtf(var + 1e-5f);
    float o[8] = {v0.x, v0.y, v0.z, v0.w, v1.x, v1.y, v1.z, v1.w};
#pragma unroll
    for (int k = 0; k < 8; ++k) {
        int c = lane * 8 + k;
        o[k] = (o[k] - mu) * rsd * gamma[c] + beta[c];
    }
    *(float4*)(out + row * 512 + lane * 8)     = (float4){o[0], o[1], o[2], o[3]};
    *(float4*)(out + row * 512 + lane * 8 + 4) = (float4){o[4], o[5], o[6], o[7]};
}

extern "C" void kernel_launch(void* const* d_in, const int* in_sizes, int n_in,
                              void* d_out, int out_size, void* d_ws, size_t ws_size,
                              hipStream_t stream) {
    const float* x     = (const float*)d_in[0];
    const int*   adj   = (const int*)d_in[1];
    const float* Wq    = (const float*)d_in[2];
    const float* Wk    = (const float*)d_in[3];
    const float* Wv    = (const float*)d_in[4];
    const float* Wo    = (const float*)d_in[5];
    const float* bo    = (const float*)d_in[6];
    const float* gamma = (const float*)d_in[7];
    const float* beta  = (const float*)d_in[8];
    float* out = (float*)d_out;

    char* ws = (char*)d_ws;
    const size_t SZ_ROWS = (size_t)NBAT * LSEQ;  // 16384
    __hip_bfloat16* xb    = (__hip_bfloat16*)(ws);              // 16.78 MB; later = partial0 = attn-out
    __hip_bfloat16* Wtqkv = (__hip_bfloat16*)(ws + 16777216);   // 1.57 MB
    __hip_bfloat16* Wto   = (__hip_bfloat16*)(ws + 18350080);   // 0.52 MB
    __hip_bfloat16* Qb    = (__hip_bfloat16*)(ws + 18874368);   // 16.78 MB
    __hip_bfloat16* Kb    = (__hip_bfloat16*)(ws + 35651584);   // 16.78 MB
    __hip_bfloat16* Vtb   = (__hip_bfloat16*)(ws + 52428800);   // 16.78 MB
    __hip_bfloat16* P1    = (__hip_bfloat16*)(ws + 69206016);   // 16.78 MB (partial1)
    float*          mlb   = (float*)        (ws + 85983232);    // 0.26 MB  (m,l per split/row)
    __hip_bfloat16* P0    = xb;   // partial0 / final attn-out alias
    __hip_bfloat16* Ab    = xb;
    (void)in_sizes; (void)n_in; (void)out_size; (void)ws_size;

    k_cvt_x<<<(SZ_ROWS * DDIM) / (256 * 4), 256, 0, stream>>>(x, xb);
    k_cvt_w<<<1024, 256, 0, stream>>>(Wq, Wk, Wv, Wo, Wtqkv, Wto);
    k_gemm_qkv<<<dim3(128, 12), 256, 0, stream>>>(xb, Wtqkv, Qb, Kb, Vtb);
    k_attn<<<256, 512, 0, stream>>>(Qb, Kb, Vtb, adj, P0, P1, mlb);
    k_combine<<<4096, 256, 0, stream>>>(P0, P1, mlb, Ab);
    k_gemm_out<<<dim3(128, 4), 256, 0, stream>>>(Ab, Wto, x, bo, out);
    k_ln<<<(unsigned)SZ_ROWS, 64, 0, stream>>>(out, gamma, beta, out);
}

// Round 5
// 291.632 us; speedup vs baseline: 2.0900x; 1.2869x over previous
//
#include <hip/hip_runtime.h>
#include <hip/hip_bf16.h>

typedef short bf16x8 __attribute__((ext_vector_type(8)));
typedef float f32x4  __attribute__((ext_vector_type(4)));
typedef unsigned int u32;

#define LSEQ 2048
#define DDIM 512
#define NBAT 8

__device__ __forceinline__ void gld_lds16(const __hip_bfloat16* g, __hip_bfloat16* l) {
    __builtin_amdgcn_global_load_lds(
        (const __attribute__((address_space(1))) u32*)g,
        (__attribute__((address_space(3))) u32*)l, 16, 0, 0);
}

// ---------------- convert x fp32 -> bf16 ----------------
__global__ void k_cvt_x(const float* __restrict__ x, __hip_bfloat16* __restrict__ xb) {
    size_t i = ((size_t)blockIdx.x * 256 + threadIdx.x) * 4;
    float4 v = *(const float4*)(x + i);
    __hip_bfloat16 h[4] = { __float2bfloat16(v.x), __float2bfloat16(v.y),
                            __float2bfloat16(v.z), __float2bfloat16(v.w) };
    *(short4*)(xb + i) = *(short4*)h;
}

// ---------------- convert + transpose weights ----------------
__global__ void k_cvt_w(const float* __restrict__ Wq, const float* __restrict__ Wk,
                        const float* __restrict__ Wv, const float* __restrict__ Wo,
                        __hip_bfloat16* __restrict__ Wtqkv, __hip_bfloat16* __restrict__ Wto) {
    __shared__ float t[32][33];
    int mat = blockIdx.x >> 8;
    int tb  = blockIdx.x & 255;
    int tk  = tb >> 4, tn = tb & 15;
    const float* W = (mat == 0) ? Wq : (mat == 1) ? Wk : (mat == 2) ? Wv : Wo;
    int c  = threadIdx.x & 31;
    int r0 = threadIdx.x >> 5;
#pragma unroll
    for (int i = 0; i < 4; ++i) {
        int r = r0 + i * 8;
        t[r][c] = W[(size_t)(tk * 32 + r) * 512 + tn * 32 + c];
    }
    __syncthreads();
    __hip_bfloat16* dst = (mat < 3) ? (Wtqkv + (size_t)mat * 512 * 512) : Wto;
#pragma unroll
    for (int i = 0; i < 4; ++i) {
        int n = r0 + i * 8;
        dst[(size_t)(tn * 32 + n) * 512 + tk * 32 + c] = __float2bfloat16(t[c][n]);
    }
}

// ---------------- fused QKV GEMM: C = xb @ [Wq|Wk|Wv]  (Bt form) ----------------
__global__ __launch_bounds__(256, 2)
void k_gemm_qkv(const __hip_bfloat16* __restrict__ A, const __hip_bfloat16* __restrict__ Bt,
                __hip_bfloat16* __restrict__ Q, __hip_bfloat16* __restrict__ Kb,
                __hip_bfloat16* __restrict__ Vt) {
    __shared__ char As[8192], Bs[8192];
    const int tid = threadIdx.x, lane = tid & 63, w = tid >> 6;
    const int l15 = lane & 15, l4 = lane >> 4;
    const int mt = blockIdx.x, nt = blockIdx.y;
    const int wr = (w >> 1) * 64, wc = (w & 1) * 64;
    f32x4 acc[4][4] = {};
    const int c0 = tid, c1 = tid + 256;
    const int r0 = c0 >> 2, o0 = c0 & 3, r1 = c1 >> 2, o1 = c1 & 3;

#pragma unroll 1
    for (int kt = 0; kt < 16; ++kt) {
        __syncthreads();
        bf16x8 a0 = *(const bf16x8*)(A + (size_t)(mt * 128 + r0) * 512 + kt * 32 + o0 * 8);
        bf16x8 a1 = *(const bf16x8*)(A + (size_t)(mt * 128 + r1) * 512 + kt * 32 + o1 * 8);
        bf16x8 b0 = *(const bf16x8*)(Bt + (size_t)(nt * 128 + r0) * 512 + kt * 32 + o0 * 8);
        bf16x8 b1 = *(const bf16x8*)(Bt + (size_t)(nt * 128 + r1) * 512 + kt * 32 + o1 * 8);
        *(bf16x8*)(As + r0 * 64 + ((o0 * 16) ^ ((((r0 >> 1) & 3)) << 4))) = a0;
        *(bf16x8*)(As + r1 * 64 + ((o1 * 16) ^ ((((r1 >> 1) & 3)) << 4))) = a1;
        *(bf16x8*)(Bs + r0 * 64 + ((o0 * 16) ^ ((((r0 >> 1) & 3)) << 4))) = b0;
        *(bf16x8*)(Bs + r1 * 64 + ((o1 * 16) ^ ((((r1 >> 1) & 3)) << 4))) = b1;
        __syncthreads();
        bf16x8 af[4], bfr[4];
#pragma unroll
        for (int i = 0; i < 4; ++i) {
            int r = wr + 16 * i + l15;
            af[i] = *(const bf16x8*)(As + r * 64 + ((16 * l4) ^ ((((r >> 1) & 3)) << 4)));
        }
#pragma unroll
        for (int j = 0; j < 4; ++j) {
            int r = wc + 16 * j + l15;
            bfr[j] = *(const bf16x8*)(Bs + r * 64 + ((16 * l4) ^ ((((r >> 1) & 3)) << 4)));
        }
#pragma unroll
        for (int i = 0; i < 4; ++i)
#pragma unroll
            for (int j = 0; j < 4; ++j)
                acc[i][j] = __builtin_amdgcn_mfma_f32_16x16x32_bf16(af[i], bfr[j], acc[i][j], 0, 0, 0);
    }
    const int which = (nt * 128) >> 9;  // uniform per block (0=q,1=k,2=v)
#pragma unroll
    for (int i = 0; i < 4; ++i) {
#pragma unroll
        for (int r = 0; r < 4; ++r) {
            int grow = mt * 128 + wr + 16 * i + (l4 << 2) + r;
#pragma unroll
            for (int j = 0; j < 4; ++j) {
                int gcol = nt * 128 + wc + 16 * j + l15;
                int cc = gcol & 511;
                __hip_bfloat16 h = __float2bfloat16(acc[i][j][r]);
                if (which == 0)      Q [(size_t)grow * 512 + cc] = h;
                else if (which == 1) Kb[(size_t)grow * 512 + cc] = h;
                else {
                    int b = grow >> 11, m = grow & 2047;
                    Vt[((size_t)b * 512 + cc) * 2048 + m] = h;
                }
            }
        }
    }
}

// ---------------- flash attention: 8 waves, dbuf KVB=32, async staging ----------------
// grid 256: b = blk&7 (XCD), qt = (blk>>3)&15 (128 q-rows), s = blk>>7 (kv half).
// Double-buffered: iter t reads buf[t&1], stages buf[(t+1)&1]; ONE barrier/iter.
// K staged via global_load_lds (row-linear, dest wave-uniform); V reg-staged.
__global__ __launch_bounds__(512, 2)
void k_attn(const __hip_bfloat16* __restrict__ Q, const __hip_bfloat16* __restrict__ Kg,
            const __hip_bfloat16* __restrict__ Vt, const int* __restrict__ adj,
            __hip_bfloat16* __restrict__ P0, __hip_bfloat16* __restrict__ P1,
            float* __restrict__ mlb) {
    __shared__ __hip_bfloat16 Kl[2][32][520];   // 66,560 B (row = 1024B data + 16B pad)
    __shared__ __hip_bfloat16 Vl[2][512][40];   // 81,920 B
    __shared__ __hip_bfloat16 Pl[8][16][40];    // 10,240 B => 158,720 B total
    const int tid = threadIdx.x, lane = tid & 63, w = tid >> 6;
    const int l15 = lane & 15, l4 = lane >> 4;
    const int b = blockIdx.x & 7, qt = (blockIdx.x >> 3) & 15, s = blockIdx.x >> 7;
    const float scale = 0.04419417382415922f;  // 1/sqrt(512)
    __hip_bfloat16* __restrict__ Op = s ? P1 : P0;

    const __hip_bfloat16* kbase = Kg + ((size_t)b * LSEQ + s * 1024) * 512;
    const __hip_bfloat16* vbase = Vt + (size_t)b * 512 * 2048 + s * 1024;
    const int* abase = adj + ((size_t)b * LSEQ + qt * 128 + w * 16 + l4 * 4) * LSEQ + s * 1024 + l15;

    // Q fragments in registers: wave's 16 rows x 512 k
    bf16x8 qf[16];
    {
        const __hip_bfloat16* qp = Q + ((size_t)b * LSEQ + qt * 128 + w * 16 + l15) * 512;
#pragma unroll
        for (int ks = 0; ks < 16; ++ks)
            qf[ks] = *(const bf16x8*)(qp + ks * 32 + l4 * 8);
    }
    f32x4 acc[32];
#pragma unroll
    for (int n = 0; n < 32; ++n) acc[n] = (f32x4){0.f, 0.f, 0.f, 0.f};
    float m_[4] = {-1e30f, -1e30f, -1e30f, -1e30f};
    float l_[4] = {0.f, 0.f, 0.f, 0.f};

    bf16x8 vld[4];
    int adjv[8];
    // ---- prologue: stage tile 0 into buf 0 ----
    {
#pragma unroll
        for (int i = 0; i < 4; ++i) {
            int r = w + i * 8;
            gld_lds16(kbase + (size_t)r * 512 + lane * 8, &Kl[0][r][0]);
        }
#pragma unroll
        for (int i = 0; i < 4; ++i) {
            int idx = tid + i * 512;
            vld[i] = *(const bf16x8*)(vbase + (size_t)(idx >> 2) * 2048 + (idx & 3) * 8);
        }
#pragma unroll
        for (int r = 0; r < 4; ++r)
#pragma unroll
            for (int n = 0; n < 2; ++n)
                adjv[r * 2 + n] = abase[(size_t)r * LSEQ + n * 16];
#pragma unroll
        for (int i = 0; i < 4; ++i) {
            int idx = tid + i * 512;
            *(bf16x8*)(&Vl[0][idx >> 2][(idx & 3) * 8]) = vld[i];
        }
    }
    __syncthreads();   // drains K global_load_lds + V ds_writes

#pragma unroll 1
    for (int t = 0; t < 32; ++t) {
        const int cur = t & 1, nxt = cur ^ 1;
        // amask for THIS iter (from regs staged last iter)
        unsigned amask = 0;
#pragma unroll
        for (int r = 0; r < 4; ++r)
#pragma unroll
            for (int n = 0; n < 2; ++n)
                amask |= (adjv[r * 2 + n] != 0 ? 1u : 0u) << (n * 4 + r);
        // ---- issue staging for t+1 (overlaps with compute below) ----
        if (t < 31) {
            const __hip_bfloat16* kp = kbase + (size_t)(t + 1) * 32 * 512;
#pragma unroll
            for (int i = 0; i < 4; ++i) {
                int r = w + i * 8;
                gld_lds16(kp + (size_t)r * 512 + lane * 8, &Kl[nxt][r][0]);
            }
            const __hip_bfloat16* vp = vbase + (t + 1) * 32;
#pragma unroll
            for (int i = 0; i < 4; ++i) {
                int idx = tid + i * 512;
                vld[i] = *(const bf16x8*)(vp + (size_t)(idx >> 2) * 2048 + (idx & 3) * 8);
            }
            const int* ap = abase + (t + 1) * 32;
#pragma unroll
            for (int r = 0; r < 4; ++r)
#pragma unroll
                for (int n = 0; n < 2; ++n)
                    adjv[r * 2 + n] = ap[(size_t)r * LSEQ + n * 16];
        }
        // ---- QK^T on buf cur: wave's 16 rows x 32 keys ----
        f32x4 sa[2];
#pragma unroll
        for (int n = 0; n < 2; ++n) sa[n] = (f32x4){0.f, 0.f, 0.f, 0.f};
        __builtin_amdgcn_s_setprio(1);
#pragma unroll
        for (int ks = 0; ks < 16; ++ks) {
#pragma unroll
            for (int n = 0; n < 2; ++n) {
                bf16x8 bk = *(const bf16x8*)(&Kl[cur][n * 16 + l15][ks * 32 + l4 * 8]);
                sa[n] = __builtin_amdgcn_mfma_f32_16x16x32_bf16(qf[ks], bk, sa[n], 0, 0, 0);
            }
        }
        __builtin_amdgcn_s_setprio(0);
        // masked row max (across the 16-lane group)
        float mx[4];
#pragma unroll
        for (int r = 0; r < 4; ++r) {
            float v = -1e30f;
#pragma unroll
            for (int n = 0; n < 2; ++n)
                if ((amask >> (n * 4 + r)) & 1) v = fmaxf(v, sa[n][r] * scale);
            v = fmaxf(v, __shfl_xor(v, 1));
            v = fmaxf(v, __shfl_xor(v, 2));
            v = fmaxf(v, __shfl_xor(v, 4));
            v = fmaxf(v, __shfl_xor(v, 8));
            mx[r] = v;
        }
        // deferred-max online softmax update (THR=8)
        float rs[4];
        bool need = false;
#pragma unroll
        for (int r = 0; r < 4; ++r) {
            rs[r] = 1.f;
            if (mx[r] > m_[r] + 8.f) { rs[r] = __expf(m_[r] - mx[r]); m_[r] = mx[r]; }
            l_[r] *= rs[r];
            need |= (rs[r] != 1.f);
        }
        if (need) {
#pragma unroll
            for (int n = 0; n < 32; ++n) {
                acc[n][0] *= rs[0]; acc[n][1] *= rs[1];
                acc[n][2] *= rs[2]; acc[n][3] *= rs[3];
            }
        }
        // p = exp(s - m) (masked -> 0); row sums
#pragma unroll
        for (int n = 0; n < 2; ++n)
#pragma unroll
            for (int r = 0; r < 4; ++r) {
                float p = ((amask >> (n * 4 + r)) & 1) ? __expf(sa[n][r] * scale - m_[r]) : 0.f;
                sa[n][r] = p;
            }
#pragma unroll
        for (int r = 0; r < 4; ++r) {
            float sm = sa[0][r] + sa[1][r];
            sm += __shfl_xor(sm, 1);
            sm += __shfl_xor(sm, 2);
            sm += __shfl_xor(sm, 4);
            sm += __shfl_xor(sm, 8);
            l_[r] += sm;
        }
        // relayout P via per-wave LDS into A-frags
#pragma unroll
        for (int n = 0; n < 2; ++n)
#pragma unroll
            for (int r = 0; r < 4; ++r)
                Pl[w][l4 * 4 + r][n * 16 + l15] = __float2bfloat16(sa[n][r]);
        // PV accumulate on buf cur
        {
            bf16x8 pf = *(const bf16x8*)(&Pl[w][l15][l4 * 8]);
            __builtin_amdgcn_s_setprio(1);
#pragma unroll
            for (int n = 0; n < 32; ++n) {
                bf16x8 bv = *(const bf16x8*)(&Vl[cur][n * 16 + l15][l4 * 8]);
                acc[n] = __builtin_amdgcn_mfma_f32_16x16x32_bf16(pf, bv, acc[n], 0, 0, 0);
            }
            __builtin_amdgcn_s_setprio(0);
        }
        // ---- late V write into next buffer ----
        if (t < 31) {
#pragma unroll
            for (int i = 0; i < 4; ++i) {
                int idx = tid + i * 512;
                *(bf16x8*)(&Vl[nxt][idx >> 2][(idx & 3) * 8]) = vld[i];
            }
        }
        __syncthreads();   // publishes buf nxt (also drains K lds-loads)
    }
    // epilogue: store raw (unnormalized) partials + (m,l) per row
#pragma unroll
    for (int r = 0; r < 4; ++r) {
        size_t row = (size_t)b * LSEQ + qt * 128 + w * 16 + l4 * 4 + r;
#pragma unroll
        for (int n = 0; n < 32; ++n)
            Op[row * 512 + n * 16 + l15] = __float2bfloat16(acc[n][r]);
        if (l15 == 0) {
            mlb[((size_t)s * 16384 + row) * 2 + 0] = m_[r];
            mlb[((size_t)s * 16384 + row) * 2 + 1] = l_[r];
        }
    }
}

// ---------------- combine the two KV-split partials (exact LSE merge) ----------------
__global__ void k_combine(const __hip_bfloat16* p0, const __hip_bfloat16* __restrict__ p1,
                          const float* __restrict__ mlb, __hip_bfloat16* outp) {
    size_t idx = (size_t)blockIdx.x * 256 + threadIdx.x;  // one thread = 8 elems
    size_t row = idx >> 6;
    int    c8  = (int)(idx & 63) * 8;
    float m0 = mlb[row * 2 + 0],             l0 = mlb[row * 2 + 1];
    float m1 = mlb[(16384 + row) * 2 + 0],   l1 = mlb[(16384 + row) * 2 + 1];
    float M  = fmaxf(m0, m1);
    float e0 = __expf(m0 - M), e1 = __expf(m1 - M);
    float den = l0 * e0 + l1 * e1;
    float inv = (den > 0.f) ? 1.f / den : 0.f;
    bf16x8 a = *(const bf16x8*)(p0 + row * 512 + c8);
    bf16x8 c = *(const bf16x8*)(p1 + row * 512 + c8);
    __hip_bfloat16 o[8];
#pragma unroll
    for (int k = 0; k < 8; ++k) {
        float fa = __bfloat162float(*(const __hip_bfloat16*)&((short*)&a)[k]);
        float fc = __bfloat162float(*(const __hip_bfloat16*)&((short*)&c)[k]);
        o[k] = __float2bfloat16((fa * e0 + fc * e1) * inv);
    }
    *(bf16x8*)(outp + row * 512 + c8) = *(bf16x8*)o;
}

// ---------------- out projection + residual + bias -> Y fp32 (into d_out) ----------------
__global__ __launch_bounds__(256, 2)
void k_gemm_out(const __hip_bfloat16* __restrict__ A, const __hip_bfloat16* __restrict__ Bt,
                const float* __restrict__ x, const float* __restrict__ bo,
                float* __restrict__ Y) {
    __shared__ char As[8192], Bs[8192];
    const int tid = threadIdx.x, lane = tid & 63, w = tid >> 6;
    const int l15 = lane & 15, l4 = lane >> 4;
    const int mt = blockIdx.x, nt = blockIdx.y;
    const int wr = (w >> 1) * 64, wc = (w & 1) * 64;
    f32x4 acc[4][4] = {};
    const int c0 = tid, c1 = tid + 256;
    const int r0 = c0 >> 2, o0 = c0 & 3, r1 = c1 >> 2, o1 = c1 & 3;

#pragma unroll 1
    for (int kt = 0; kt < 16; ++kt) {
        __syncthreads();
        bf16x8 a0 = *(const bf16x8*)(A + (size_t)(mt * 128 + r0) * 512 + kt * 32 + o0 * 8);
        bf16x8 a1 = *(const bf16x8*)(A + (size_t)(mt * 128 + r1) * 512 + kt * 32 + o1 * 8);
        bf16x8 b0 = *(const bf16x8*)(Bt + (size_t)(nt * 128 + r0) * 512 + kt * 32 + o0 * 8);
        bf16x8 b1 = *(const bf16x8*)(Bt + (size_t)(nt * 128 + r1) * 512 + kt * 32 + o1 * 8);
        *(bf16x8*)(As + r0 * 64 + ((o0 * 16) ^ ((((r0 >> 1) & 3)) << 4))) = a0;
        *(bf16x8*)(As + r1 * 64 + ((o1 * 16) ^ ((((r1 >> 1) & 3)) << 4))) = a1;
        *(bf16x8*)(Bs + r0 * 64 + ((o0 * 16) ^ ((((r0 >> 1) & 3)) << 4))) = b0;
        *(bf16x8*)(Bs + r1 * 64 + ((o1 * 16) ^ ((((r1 >> 1) & 3)) << 4))) = b1;
        __syncthreads();
        bf16x8 af[4], bfr[4];
#pragma unroll
        for (int i = 0; i < 4; ++i) {
            int r = wr + 16 * i + l15;
            af[i] = *(const bf16x8*)(As + r * 64 + ((16 * l4) ^ ((((r >> 1) & 3)) << 4)));
        }
#pragma unroll
        for (int j = 0; j < 4; ++j) {
            int r = wc + 16 * j + l15;
            bfr[j] = *(const bf16x8*)(Bs + r * 64 + ((16 * l4) ^ ((((r >> 1) & 3)) << 4)));
        }
#pragma unroll
        for (int i = 0; i < 4; ++i)
#pragma unroll
            for (int j = 0; j < 4; ++j)
                acc[i][j] = __builtin_amdgcn_mfma_f32_16x16x32_bf16(af[i], bfr[j], acc[i][j], 0, 0, 0);
    }
#pragma unroll
    for (int i = 0; i < 4; ++i) {
#pragma unroll
        for (int r = 0; r < 4; ++r) {
            size_t grow = (size_t)mt * 128 + wr + 16 * i + (l4 << 2) + r;
#pragma unroll
            for (int j = 0; j < 4; ++j) {
                int gcol = nt * 128 + wc + 16 * j + l15;
                Y[grow * 512 + gcol] = x[grow * 512 + gcol] + acc[i][j][r] + bo[gcol];
            }
        }
    }
}

// ---------------- in-place LayerNorm over rows of 512 ----------------
__global__ void k_ln(float* __restrict__ Y, const float* __restrict__ gamma,
                     const float* __restrict__ beta, float* __restrict__ out) {
    size_t row = blockIdx.x;
    int lane = threadIdx.x;
    float* y = Y + row * 512;
    float4 v0 = *(const float4*)(y + lane * 8);
    float4 v1 = *(const float4*)(y + lane * 8 + 4);
    float s = v0.x + v0.y + v0.z + v0.w + v1.x + v1.y + v1.z + v1.w;
    float q = v0.x * v0.x + v0.y * v0.y + v0.z * v0.z + v0.w * v0.w +
              v1.x * v1.x + v1.y * v1.y + v1.z * v1.z + v1.w * v1.w;
#pragma unroll
    for (int off = 1; off < 64; off <<= 1) {
        s += __shfl_xor(s, off);
        q += __shfl_xor(q, off);
    }
    float mu = s * (1.f / 512.f);
    float var = q * (1.f / 512.f) - mu * mu;
    float rsd = rsqrtf(var + 1e-5f);
    float o[8] = {v0.x, v0.y, v0.z, v0.w, v1.x, v1.y, v1.z, v1.w};
#pragma unroll
    for (int k = 0; k < 8; ++k) {
        int c = lane * 8 + k;
        o[k] = (o[k] - mu) * rsd * gamma[c] + beta[c];
    }
    *(float4*)(out + row * 512 + lane * 8)     = (float4){o[0], o[1], o[2], o[3]};
    *(float4*)(out + row * 512 + lane * 8 + 4) = (float4){o[4], o[5], o[6], o[7]};
}

extern "C" void kernel_launch(void* const* d_in, const int* in_sizes, int n_in,
                              void* d_out, int out_size, void* d_ws, size_t ws_size,
                              hipStream_t stream) {
    const float* x     = (const float*)d_in[0];
    const int*   adj   = (const int*)d_in[1];
    const float* Wq    = (const float*)d_in[2];
    const float* Wk    = (const float*)d_in[3];
    const float* Wv    = (const float*)d_in[4];
    const float* Wo    = (const float*)d_in[5];
    const float* bo    = (const float*)d_in[6];
    const float* gamma = (const float*)d_in[7];
    const float* beta  = (const float*)d_in[8];
    float* out = (float*)d_out;

    char* ws = (char*)d_ws;
    const size_t SZ_ROWS = (size_t)NBAT * LSEQ;  // 16384
    __hip_bfloat16* xb    = (__hip_bfloat16*)(ws);              // 16.78 MB; later = partial0 = attn-out
    __hip_bfloat16* Wtqkv = (__hip_bfloat16*)(ws + 16777216);   // 1.57 MB
    __hip_bfloat16* Wto   = (__hip_bfloat16*)(ws + 18350080);   // 0.52 MB
    __hip_bfloat16* Qb    = (__hip_bfloat16*)(ws + 18874368);   // 16.78 MB
    __hip_bfloat16* Kb    = (__hip_bfloat16*)(ws + 35651584);   // 16.78 MB
    __hip_bfloat16* Vtb   = (__hip_bfloat16*)(ws + 52428800);   // 16.78 MB
    __hip_bfloat16* P1    = (__hip_bfloat16*)(ws + 69206016);   // 16.78 MB (partial1)
    float*          mlb   = (float*)        (ws + 85983232);    // 0.26 MB  (m,l per split/row)
    __hip_bfloat16* P0    = xb;   // partial0 / final attn-out alias
    __hip_bfloat16* Ab    = xb;
    (void)in_sizes; (void)n_in; (void)out_size; (void)ws_size;

    k_cvt_x<<<(SZ_ROWS * DDIM) / (256 * 4), 256, 0, stream>>>(x, xb);
    k_cvt_w<<<1024, 256, 0, stream>>>(Wq, Wk, Wv, Wo, Wtqkv, Wto);
    k_gemm_qkv<<<dim3(128, 12), 256, 0, stream>>>(xb, Wtqkv, Qb, Kb, Vtb);
    k_attn<<<256, 512, 0, stream>>>(Qb, Kb, Vtb, adj, P0, P1, mlb);
    k_combine<<<4096, 256, 0, stream>>>(P0, P1, mlb, Ab);
    k_gemm_out<<<dim3(128, 4), 256, 0, stream>>>(Ab, Wto, x, bo, out);
    k_ln<<<(unsigned)SZ_ROWS, 64, 0, stream>>>(out, gamma, beta, out);
}

// Round 6
// 249.330 us; speedup vs baseline: 2.4446x; 1.1697x over previous
//
#include <hip/hip_runtime.h>
#include <hip/hip_bf16.h>

typedef short bf16x8 __attribute__((ext_vector_type(8)));
typedef float f32x4  __attribute__((ext_vector_type(4)));
typedef unsigned int u32;

#define LSEQ 2048
#define DDIM 512
#define NBAT 8

__device__ __forceinline__ void gld_lds16(const __hip_bfloat16* g, __hip_bfloat16* l) {
    __builtin_amdgcn_global_load_lds(
        (const __attribute__((address_space(1))) u32*)g,
        (__attribute__((address_space(3))) u32*)l, 16, 0, 0);
}

// ---------------- convert x fp32 -> bf16 ----------------
__global__ void k_cvt_x(const float* __restrict__ x, __hip_bfloat16* __restrict__ xb) {
    size_t i = ((size_t)blockIdx.x * 256 + threadIdx.x) * 4;
    float4 v = *(const float4*)(x + i);
    __hip_bfloat16 h[4] = { __float2bfloat16(v.x), __float2bfloat16(v.y),
                            __float2bfloat16(v.z), __float2bfloat16(v.w) };
    *(short4*)(xb + i) = *(short4*)h;
}

// ---------------- convert + transpose weights ----------------
__global__ void k_cvt_w(const float* __restrict__ Wq, const float* __restrict__ Wk,
                        const float* __restrict__ Wv, const float* __restrict__ Wo,
                        __hip_bfloat16* __restrict__ Wtqkv, __hip_bfloat16* __restrict__ Wto) {
    __shared__ float t[32][33];
    int mat = blockIdx.x >> 8;
    int tb  = blockIdx.x & 255;
    int tk  = tb >> 4, tn = tb & 15;
    const float* W = (mat == 0) ? Wq : (mat == 1) ? Wk : (mat == 2) ? Wv : Wo;
    int c  = threadIdx.x & 31;
    int r0 = threadIdx.x >> 5;
#pragma unroll
    for (int i = 0; i < 4; ++i) {
        int r = r0 + i * 8;
        t[r][c] = W[(size_t)(tk * 32 + r) * 512 + tn * 32 + c];
    }
    __syncthreads();
    __hip_bfloat16* dst = (mat < 3) ? (Wtqkv + (size_t)mat * 512 * 512) : Wto;
#pragma unroll
    for (int i = 0; i < 4; ++i) {
        int n = r0 + i * 8;
        dst[(size_t)(tn * 32 + n) * 512 + tk * 32 + c] = __float2bfloat16(t[c][n]);
    }
}

// ---------------- fused QKV GEMM (m97-style gld_lds staging) ----------------
__global__ __launch_bounds__(256, 2)
void k_gemm_qkv(const __hip_bfloat16* __restrict__ A, const __hip_bfloat16* __restrict__ Bt,
                __hip_bfloat16* __restrict__ Q, __hip_bfloat16* __restrict__ Kb,
                __hip_bfloat16* __restrict__ Vt) {
    __shared__ __hip_bfloat16 As[128][32], Bs[128][32];   // 8 KB each, linear
    const int tid = threadIdx.x, lane = tid & 63, w = tid >> 6;
    const int l15 = lane & 15, l4 = lane >> 4;
    const int mt = blockIdx.x, nt = blockIdx.y;
    const int wr = (w >> 1) * 64, wc = (w & 1) * 64;
    const int sr = lane >> 2, so = (lane & 3) * 8;        // staging row/col within 16-row chunk
    f32x4 acc[4][4] = {};

#pragma unroll 1
    for (int kt = 0; kt < 16; ++kt) {
        __syncthreads();
        // stage: per wave 2 A-chunks + 2 B-chunks of 16 rows x 32 k (1 KB each)
#pragma unroll
        for (int i = 0; i < 2; ++i) {
            int r0 = w * 32 + i * 16;
            gld_lds16(A  + (size_t)(mt * 128 + r0 + sr) * 512 + kt * 32 + so, &As[r0][0]);
            gld_lds16(Bt + (size_t)(nt * 128 + r0 + sr) * 512 + kt * 32 + so, &Bs[r0][0]);
        }
        __syncthreads();
        bf16x8 af[4], bfr[4];
#pragma unroll
        for (int i = 0; i < 4; ++i)
            af[i] = *(const bf16x8*)(&As[wr + 16 * i + l15][l4 * 8]);
#pragma unroll
        for (int j = 0; j < 4; ++j)
            bfr[j] = *(const bf16x8*)(&Bs[wc + 16 * j + l15][l4 * 8]);
        __builtin_amdgcn_s_setprio(1);
#pragma unroll
        for (int i = 0; i < 4; ++i)
#pragma unroll
            for (int j = 0; j < 4; ++j)
                acc[i][j] = __builtin_amdgcn_mfma_f32_16x16x32_bf16(af[i], bfr[j], acc[i][j], 0, 0, 0);
        __builtin_amdgcn_s_setprio(0);
    }
    const int which = (nt * 128) >> 9;  // uniform per block (0=q,1=k,2=v)
#pragma unroll
    for (int i = 0; i < 4; ++i) {
#pragma unroll
        for (int r = 0; r < 4; ++r) {
            int grow = mt * 128 + wr + 16 * i + (l4 << 2) + r;
#pragma unroll
            for (int j = 0; j < 4; ++j) {
                int gcol = nt * 128 + wc + 16 * j + l15;
                int cc = gcol & 511;
                __hip_bfloat16 h = __float2bfloat16(acc[i][j][r]);
                if (which == 0)      Q [(size_t)grow * 512 + cc] = h;
                else if (which == 1) Kb[(size_t)grow * 512 + cc] = h;
                else {
                    int b = grow >> 11, m = grow & 2047;
                    Vt[((size_t)b * 512 + cc) * 2048 + m] = h;
                }
            }
        }
    }
}

// ---------------- flash attention: 8 waves, dbuf KVB=32, all-async staging ----------------
// grid 256: b = blk&7 (XCD), qt = (blk>>3)&15 (128 q-rows), s = blk>>7 (kv half).
// Iter t reads buf[t&1], stages buf[t^1] via global_load_lds (K and V); ONE barrier/iter.
__global__ __launch_bounds__(512, 2)
void k_attn(const __hip_bfloat16* __restrict__ Q, const __hip_bfloat16* __restrict__ Kg,
            const __hip_bfloat16* __restrict__ Vt, const int* __restrict__ adj,
            __hip_bfloat16* __restrict__ P0, __hip_bfloat16* __restrict__ P1,
            float* __restrict__ mlb) {
    __shared__ __hip_bfloat16 Kl[2][32][520];   // 66,560 B (1024B data + 16B pad per row)
    __shared__ __hip_bfloat16 Vl[2][512][32];   // 65,536 B (linear 64B rows for gld_lds)
    __shared__ __hip_bfloat16 Pl[8][16][40];    // 10,240 B => 142,336 B total
    const int tid = threadIdx.x, lane = tid & 63, w = tid >> 6;
    const int l15 = lane & 15, l4 = lane >> 4;
    const int b = blockIdx.x & 7, qt = (blockIdx.x >> 3) & 15, s = blockIdx.x >> 7;
    const float scale = 0.04419417382415922f;  // 1/sqrt(512)
    __hip_bfloat16* __restrict__ Op = s ? P1 : P0;

    const __hip_bfloat16* kbase = Kg + ((size_t)b * LSEQ + s * 1024) * 512;
    const __hip_bfloat16* vbase = Vt + (size_t)b * 512 * 2048 + s * 1024;
    const int* abase = adj + ((size_t)b * LSEQ + qt * 128 + w * 16 + l4 * 4) * LSEQ + s * 1024 + l15;
    const int vsr = lane >> 2, vso = (lane & 3) * 8;  // V staging row/col within 16-row chunk

    // Q fragments in registers: wave's 16 rows x 512 k
    bf16x8 qf[16];
    {
        const __hip_bfloat16* qp = Q + ((size_t)b * LSEQ + qt * 128 + w * 16 + l15) * 512;
#pragma unroll
        for (int ks = 0; ks < 16; ++ks)
            qf[ks] = *(const bf16x8*)(qp + ks * 32 + l4 * 8);
    }
    f32x4 acc[32];
#pragma unroll
    for (int n = 0; n < 32; ++n) acc[n] = (f32x4){0.f, 0.f, 0.f, 0.f};
    float m_[4] = {-1e30f, -1e30f, -1e30f, -1e30f};
    float l_[4] = {0.f, 0.f, 0.f, 0.f};

    int adjv[8];
    // ---- prologue: stage tile 0 into buf 0 ----
    {
#pragma unroll
        for (int i = 0; i < 4; ++i) {
            int r = w + i * 8;
            gld_lds16(kbase + (size_t)r * 512 + lane * 8, &Kl[0][r][0]);
        }
#pragma unroll
        for (int i = 0; i < 4; ++i) {
            int r0 = (w * 4 + i) * 16;
            gld_lds16(vbase + (size_t)(r0 + vsr) * 2048 + vso, &Vl[0][r0][0]);
        }
#pragma unroll
        for (int r = 0; r < 4; ++r)
#pragma unroll
            for (int n = 0; n < 2; ++n)
                adjv[r * 2 + n] = abase[(size_t)r * LSEQ + n * 16];
    }
    __syncthreads();   // drains all global_load_lds

#pragma unroll 1
    for (int t = 0; t < 32; ++t) {
        const int cur = t & 1, nxt = cur ^ 1;
        // amask for THIS iter (from regs staged last iter)
        unsigned amask = 0;
#pragma unroll
        for (int r = 0; r < 4; ++r)
#pragma unroll
            for (int n = 0; n < 2; ++n)
                amask |= (adjv[r * 2 + n] != 0 ? 1u : 0u) << (n * 4 + r);
        // ---- issue staging for t+1 (overlaps with compute below) ----
        if (t < 31) {
            const __hip_bfloat16* kp = kbase + (size_t)(t + 1) * 32 * 512;
#pragma unroll
            for (int i = 0; i < 4; ++i) {
                int r = w + i * 8;
                gld_lds16(kp + (size_t)r * 512 + lane * 8, &Kl[nxt][r][0]);
            }
            const __hip_bfloat16* vp = vbase + (t + 1) * 32;
#pragma unroll
            for (int i = 0; i < 4; ++i) {
                int r0 = (w * 4 + i) * 16;
                gld_lds16(vp + (size_t)(r0 + vsr) * 2048 + vso, &Vl[nxt][r0][0]);
            }
            const int* ap = abase + (t + 1) * 32;
#pragma unroll
            for (int r = 0; r < 4; ++r)
#pragma unroll
                for (int n = 0; n < 2; ++n)
                    adjv[r * 2 + n] = ap[(size_t)r * LSEQ + n * 16];
        }
        // ---- QK^T on buf cur: wave's 16 rows x 32 keys ----
        f32x4 sa[2];
#pragma unroll
        for (int n = 0; n < 2; ++n) sa[n] = (f32x4){0.f, 0.f, 0.f, 0.f};
        __builtin_amdgcn_s_setprio(1);
#pragma unroll
        for (int ks = 0; ks < 16; ++ks) {
#pragma unroll
            for (int n = 0; n < 2; ++n) {
                bf16x8 bk = *(const bf16x8*)(&Kl[cur][n * 16 + l15][ks * 32 + l4 * 8]);
                sa[n] = __builtin_amdgcn_mfma_f32_16x16x32_bf16(qf[ks], bk, sa[n], 0, 0, 0);
            }
        }
        __builtin_amdgcn_s_setprio(0);
        // masked row max (across the 16-lane group)
        float mx[4];
#pragma unroll
        for (int r = 0; r < 4; ++r) {
            float v = -1e30f;
#pragma unroll
            for (int n = 0; n < 2; ++n)
                if ((amask >> (n * 4 + r)) & 1) v = fmaxf(v, sa[n][r] * scale);
            v = fmaxf(v, __shfl_xor(v, 1));
            v = fmaxf(v, __shfl_xor(v, 2));
            v = fmaxf(v, __shfl_xor(v, 4));
            v = fmaxf(v, __shfl_xor(v, 8));
            mx[r] = v;
        }
        // deferred-max online softmax update (THR=8)
        float rs[4];
        bool need = false;
#pragma unroll
        for (int r = 0; r < 4; ++r) {
            rs[r] = 1.f;
            if (mx[r] > m_[r] + 8.f) { rs[r] = __expf(m_[r] - mx[r]); m_[r] = mx[r]; }
            l_[r] *= rs[r];
            need |= (rs[r] != 1.f);
        }
        if (need) {
#pragma unroll
            for (int n = 0; n < 32; ++n) {
                acc[n][0] *= rs[0]; acc[n][1] *= rs[1];
                acc[n][2] *= rs[2]; acc[n][3] *= rs[3];
            }
        }
        // p = exp(s - m) (masked -> 0); row sums
#pragma unroll
        for (int n = 0; n < 2; ++n)
#pragma unroll
            for (int r = 0; r < 4; ++r) {
                float p = ((amask >> (n * 4 + r)) & 1) ? __expf(sa[n][r] * scale - m_[r]) : 0.f;
                sa[n][r] = p;
            }
#pragma unroll
        for (int r = 0; r < 4; ++r) {
            float sm = sa[0][r] + sa[1][r];
            sm += __shfl_xor(sm, 1);
            sm += __shfl_xor(sm, 2);
            sm += __shfl_xor(sm, 4);
            sm += __shfl_xor(sm, 8);
            l_[r] += sm;
        }
        // relayout P via per-wave LDS into A-frags
#pragma unroll
        for (int n = 0; n < 2; ++n)
#pragma unroll
            for (int r = 0; r < 4; ++r)
                Pl[w][l4 * 4 + r][n * 16 + l15] = __float2bfloat16(sa[n][r]);
        // PV accumulate on buf cur
        {
            bf16x8 pf = *(const bf16x8*)(&Pl[w][l15][l4 * 8]);
            __builtin_amdgcn_s_setprio(1);
#pragma unroll
            for (int n = 0; n < 32; ++n) {
                bf16x8 bv = *(const bf16x8*)(&Vl[cur][n * 16 + l15][l4 * 8]);
                acc[n] = __builtin_amdgcn_mfma_f32_16x16x32_bf16(pf, bv, acc[n], 0, 0, 0);
            }
            __builtin_amdgcn_s_setprio(0);
        }
        __syncthreads();   // publishes buf nxt (drains K/V gld_lds + Pl use)
    }
    // epilogue: store raw (unnormalized) partials + (m,l) per row
#pragma unroll
    for (int r = 0; r < 4; ++r) {
        size_t row = (size_t)b * LSEQ + qt * 128 + w * 16 + l4 * 4 + r;
#pragma unroll
        for (int n = 0; n < 32; ++n)
            Op[row * 512 + n * 16 + l15] = __float2bfloat16(acc[n][r]);
        if (l15 == 0) {
            mlb[((size_t)s * 16384 + row) * 2 + 0] = m_[r];
            mlb[((size_t)s * 16384 + row) * 2 + 1] = l_[r];
        }
    }
}

// ---------------- combine the two KV-split partials (exact LSE merge) ----------------
__global__ void k_combine(const __hip_bfloat16* p0, const __hip_bfloat16* __restrict__ p1,
                          const float* __restrict__ mlb, __hip_bfloat16* outp) {
    size_t idx = (size_t)blockIdx.x * 256 + threadIdx.x;  // one thread = 8 elems
    size_t row = idx >> 6;
    int    c8  = (int)(idx & 63) * 8;
    float m0 = mlb[row * 2 + 0],             l0 = mlb[row * 2 + 1];
    float m1 = mlb[(16384 + row) * 2 + 0],   l1 = mlb[(16384 + row) * 2 + 1];
    float M  = fmaxf(m0, m1);
    float e0 = __expf(m0 - M), e1 = __expf(m1 - M);
    float den = l0 * e0 + l1 * e1;
    float inv = (den > 0.f) ? 1.f / den : 0.f;
    bf16x8 a = *(const bf16x8*)(p0 + row * 512 + c8);
    bf16x8 c = *(const bf16x8*)(p1 + row * 512 + c8);
    __hip_bfloat16 o[8];
#pragma unroll
    for (int k = 0; k < 8; ++k) {
        float fa = __bfloat162float(*(const __hip_bfloat16*)&((short*)&a)[k]);
        float fc = __bfloat162float(*(const __hip_bfloat16*)&((short*)&c)[k]);
        o[k] = __float2bfloat16((fa * e0 + fc * e1) * inv);
    }
    *(bf16x8*)(outp + row * 512 + c8) = *(bf16x8*)o;
}

// ---------------- out projection + residual + bias -> Y fp32 (m97-style staging) ----------------
__global__ __launch_bounds__(256, 2)
void k_gemm_out(const __hip_bfloat16* __restrict__ A, const __hip_bfloat16* __restrict__ Bt,
                const float* __restrict__ x, const float* __restrict__ bo,
                float* __restrict__ Y) {
    __shared__ __hip_bfloat16 As[128][32], Bs[128][32];
    const int tid = threadIdx.x, lane = tid & 63, w = tid >> 6;
    const int l15 = lane & 15, l4 = lane >> 4;
    const int mt = blockIdx.x, nt = blockIdx.y;
    const int wr = (w >> 1) * 64, wc = (w & 1) * 64;
    const int sr = lane >> 2, so = (lane & 3) * 8;
    f32x4 acc[4][4] = {};

#pragma unroll 1
    for (int kt = 0; kt < 16; ++kt) {
        __syncthreads();
#pragma unroll
        for (int i = 0; i < 2; ++i) {
            int r0 = w * 32 + i * 16;
            gld_lds16(A  + (size_t)(mt * 128 + r0 + sr) * 512 + kt * 32 + so, &As[r0][0]);
            gld_lds16(Bt + (size_t)(nt * 128 + r0 + sr) * 512 + kt * 32 + so, &Bs[r0][0]);
        }
        __syncthreads();
        bf16x8 af[4], bfr[4];
#pragma unroll
        for (int i = 0; i < 4; ++i)
            af[i] = *(const bf16x8*)(&As[wr + 16 * i + l15][l4 * 8]);
#pragma unroll
        for (int j = 0; j < 4; ++j)
            bfr[j] = *(const bf16x8*)(&Bs[wc + 16 * j + l15][l4 * 8]);
        __builtin_amdgcn_s_setprio(1);
#pragma unroll
        for (int i = 0; i < 4; ++i)
#pragma unroll
            for (int j = 0; j < 4; ++j)
                acc[i][j] = __builtin_amdgcn_mfma_f32_16x16x32_bf16(af[i], bfr[j], acc[i][j], 0, 0, 0);
        __builtin_amdgcn_s_setprio(0);
    }
#pragma unroll
    for (int i = 0; i < 4; ++i) {
#pragma unroll
        for (int r = 0; r < 4; ++r) {
            size_t grow = (size_t)mt * 128 + wr + 16 * i + (l4 << 2) + r;
#pragma unroll
            for (int j = 0; j < 4; ++j) {
                int gcol = nt * 128 + wc + 16 * j + l15;
                Y[grow * 512 + gcol] = x[grow * 512 + gcol] + acc[i][j][r] + bo[gcol];
            }
        }
    }
}

// ---------------- in-place LayerNorm over rows of 512 ----------------
__global__ void k_ln(float* __restrict__ Y, const float* __restrict__ gamma,
                     const float* __restrict__ beta, float* __restrict__ out) {
    size_t row = blockIdx.x;
    int lane = threadIdx.x;
    float* y = Y + row * 512;
    float4 v0 = *(const float4*)(y + lane * 8);
    float4 v1 = *(const float4*)(y + lane * 8 + 4);
    float s = v0.x + v0.y + v0.z + v0.w + v1.x + v1.y + v1.z + v1.w;
    float q = v0.x * v0.x + v0.y * v0.y + v0.z * v0.z + v0.w * v0.w +
              v1.x * v1.x + v1.y * v1.y + v1.z * v1.z + v1.w * v1.w;
#pragma unroll
    for (int off = 1; off < 64; off <<= 1) {
        s += __shfl_xor(s, off);
        q += __shfl_xor(q, off);
    }
    float mu = s * (1.f / 512.f);
    float var = q * (1.f / 512.f) - mu * mu;
    float rsd = rsqrtf(var + 1e-5f);
    float o[8] = {v0.x, v0.y, v0.z, v0.w, v1.x, v1.y, v1.z, v1.w};
#pragma unroll
    for (int k = 0; k < 8; ++k) {
        int c = lane * 8 + k;
        o[k] = (o[k] - mu) * rsd * gamma[c] + beta[c];
    }
    *(float4*)(out + row * 512 + lane * 8)     = (float4){o[0], o[1], o[2], o[3]};
    *(float4*)(out + row * 512 + lane * 8 + 4) = (float4){o[4], o[5], o[6], o[7]};
}

extern "C" void kernel_launch(void* const* d_in, const int* in_sizes, int n_in,
                              void* d_out, int out_size, void* d_ws, size_t ws_size,
                              hipStream_t stream) {
    const float* x     = (const float*)d_in[0];
    const int*   adj   = (const int*)d_in[1];
    const float* Wq    = (const float*)d_in[2];
    const float* Wk    = (const float*)d_in[3];
    const float* Wv    = (const float*)d_in[4];
    const float* Wo    = (const float*)d_in[5];
    const float* bo    = (const float*)d_in[6];
    const float* gamma = (const float*)d_in[7];
    const float* beta  = (const float*)d_in[8];
    float* out = (float*)d_out;

    char* ws = (char*)d_ws;
    const size_t SZ_ROWS = (size_t)NBAT * LSEQ;  // 16384
    __hip_bfloat16* xb    = (__hip_bfloat16*)(ws);              // 16.78 MB; later = partial0 = attn-out
    __hip_bfloat16* Wtqkv = (__hip_bfloat16*)(ws + 16777216);   // 1.57 MB
    __hip_bfloat16* Wto   = (__hip_bfloat16*)(ws + 18350080);   // 0.52 MB
    __hip_bfloat16* Qb    = (__hip_bfloat16*)(ws + 18874368);   // 16.78 MB
    __hip_bfloat16* Kb    = (__hip_bfloat16*)(ws + 35651584);   // 16.78 MB
    __hip_bfloat16* Vtb   = (__hip_bfloat16*)(ws + 52428800);   // 16.78 MB
    __hip_bfloat16* P1    = (__hip_bfloat16*)(ws + 69206016);   // 16.78 MB (partial1)
    float*          mlb   = (float*)        (ws + 85983232);    // 0.26 MB  (m,l per split/row)
    __hip_bfloat16* P0    = xb;   // partial0 / final attn-out alias
    __hip_bfloat16* Ab    = xb;
    (void)in_sizes; (void)n_in; (void)out_size; (void)ws_size;

    k_cvt_x<<<(SZ_ROWS * DDIM) / (256 * 4), 256, 0, stream>>>(x, xb);
    k_cvt_w<<<1024, 256, 0, stream>>>(Wq, Wk, Wv, Wo, Wtqkv, Wto);
    k_gemm_qkv<<<dim3(128, 12), 256, 0, stream>>>(xb, Wtqkv, Qb, Kb, Vtb);
    k_attn<<<256, 512, 0, stream>>>(Qb, Kb, Vtb, adj, P0, P1, mlb);
    k_combine<<<4096, 256, 0, stream>>>(P0, P1, mlb, Ab);
    k_gemm_out<<<dim3(128, 4), 256, 0, stream>>>(Ab, Wto, x, bo, out);
    k_ln<<<(unsigned)SZ_ROWS, 64, 0, stream>>>(out, gamma, beta, out);
}